// Round 2
// baseline (1604.830 us; speedup 1.0000x reference)
//
#include <hip/hip_runtime.h>
#include <hip/hip_bf16.h>
#include <math.h>

// Problem constants (fixed by reference)
#define D_INF 768
#define DMODEL 512
#define NHEAD 4
#define HDIM 128
#define FFDIM 2048
#define BATCH 64
#define SEQ 512
#define ROWS (BATCH * SEQ)  // 32768

typedef __attribute__((ext_vector_type(8))) short short8;
typedef __attribute__((ext_vector_type(4))) short short4v;
typedef __attribute__((ext_vector_type(4))) float f32x4;

__device__ inline unsigned short f2bf(float f) {  // RNE fp32->bf16 (finite inputs)
  unsigned int u = __float_as_uint(f);
  return (unsigned short)((u + 0x7fffu + ((u >> 16) & 1u)) >> 16);
}
__device__ inline float bf2f(unsigned short h) {
  return __uint_as_float(((unsigned int)h) << 16);
}

// ---------------------------------------------------------------------------
// fp32 -> bf16 cast (weights, once per launch)
// ---------------------------------------------------------------------------
__global__ __launch_bounds__(256) void cast_bf16(const float* __restrict__ src,
                                                 unsigned short* __restrict__ dst,
                                                 int n) {
  int i = (blockIdx.x * 256 + threadIdx.x) * 4;
  if (i < n) {
    float4 v = *(const float4*)&src[i];
    short4v s;
    s.x = (short)f2bf(v.x); s.y = (short)f2bf(v.y);
    s.z = (short)f2bf(v.z); s.w = (short)f2bf(v.w);
    *(short4v*)&dst[i] = s;
  }
}

// ---------------------------------------------------------------------------
// MFMA bf16 GEMM:  C[M,N] = act(A[M,K] @ W[N,K]^T + bias[N]), fp32 accumulate.
// 128x128 block tile, BK=32, 256 threads = 4 waves (2x2), 64x64 per wave,
// 4x4 fragments of mfma_f32_16x16x32_bf16 per wave per K-step.
// Fragment layouts (HW-verified m89/m91/m92): A: row=lane&15, k=8*(lane>>4)+j;
// B: col=lane&15, same k; C/D: col=lane&15, row=4*(lane>>4)+reg.
// ABF: A is bf16 (ushort) else fp32 (converted during staging).
// OBF: C written as bf16 else fp32.
// ---------------------------------------------------------------------------
template <int RELU, int OBF, int ABF>
__global__ __launch_bounds__(256) void gemm_mfma(const void* __restrict__ Av,
                                                 const unsigned short* __restrict__ W,
                                                 const float* __restrict__ bias,
                                                 void* __restrict__ Cv,
                                                 int M, int N, int K) {
  __shared__ short As[128][32];  // [m][k] bf16
  __shared__ short Ws[128][32];  // [n][k] bf16
  const int t = threadIdx.x;
  const int m0 = blockIdx.y * 128, n0 = blockIdx.x * 128;
  const int wid = t >> 6, lane = t & 63;
  const int wr = wid >> 1, wc = wid & 1;
  const int l15 = lane & 15, k8 = lane >> 4;

  f32x4 acc[4][4];
#pragma unroll
  for (int i = 0; i < 4; ++i)
#pragma unroll
    for (int j = 0; j < 4; ++j) acc[i][j] = (f32x4)0.0f;

  for (int kt = 0; kt < K; kt += 32) {
    __syncthreads();  // previous iter's fragment reads done before overwrite
    if (ABF) {
      const unsigned short* A = (const unsigned short*)Av;
#pragma unroll
      for (int i = 0; i < 2; ++i) {
        int g = t + i * 256;  // 0..511 (16B chunks of 128x32 bf16 tile)
        int r = g >> 2, f = g & 3;
        short8 v = *(const short8*)(A + (size_t)(m0 + r) * K + kt + f * 8);
        *(short8*)&As[r][f * 8] = v;
      }
    } else {
      const float* A = (const float*)Av;
#pragma unroll
      for (int i = 0; i < 4; ++i) {
        int g = t + i * 256;  // 0..1023 (float4 chunks of 128x32 fp32 tile)
        int r = g >> 3, f = g & 7;
        float4 v = *(const float4*)(A + (size_t)(m0 + r) * K + kt + f * 4);
        short4v s;
        s.x = (short)f2bf(v.x); s.y = (short)f2bf(v.y);
        s.z = (short)f2bf(v.z); s.w = (short)f2bf(v.w);
        *(short4v*)&As[r][f * 4] = s;
      }
    }
#pragma unroll
    for (int i = 0; i < 2; ++i) {
      int g = t + i * 256;
      int r = g >> 2, f = g & 3;
      short8 v = *(const short8*)(W + (size_t)(n0 + r) * K + kt + f * 8);
      *(short8*)&Ws[r][f * 8] = v;
    }
    __syncthreads();

    short8 af[4], bg[4];
#pragma unroll
    for (int i = 0; i < 4; ++i)
      af[i] = *(const short8*)&As[wr * 64 + i * 16 + l15][k8 * 8];
#pragma unroll
    for (int j = 0; j < 4; ++j)
      bg[j] = *(const short8*)&Ws[wc * 64 + j * 16 + l15][k8 * 8];
#pragma unroll
    for (int i = 0; i < 4; ++i)
#pragma unroll
      for (int j = 0; j < 4; ++j)
        acc[i][j] = __builtin_amdgcn_mfma_f32_16x16x32_bf16(af[i], bg[j],
                                                            acc[i][j], 0, 0, 0);
  }

  // Epilogue: bias (+ReLU), store fp32 or bf16
#pragma unroll
  for (int j = 0; j < 4; ++j) {
    int col = n0 + wc * 64 + j * 16 + l15;
    float bv = bias[col];
#pragma unroll
    for (int i = 0; i < 4; ++i) {
      int rbase = m0 + wr * 64 + i * 16 + k8 * 4;
#pragma unroll
      for (int r = 0; r < 4; ++r) {
        float v = acc[i][j][r] + bv;
        if (RELU) v = fmaxf(v, 0.f);
        if (OBF)
          ((unsigned short*)Cv)[(size_t)(rbase + r) * N + col] = f2bf(v);
        else
          ((float*)Cv)[(size_t)(rbase + r) * N + col] = v;
      }
    }
  }
}

// ---------------------------------------------------------------------------
// Fused flash-attention (fp32 vector math, bf16 QKV input; unmasked softmax
// per reference). Grid: (S/64 q-tiles, H, B). Block 256 threads.
// qkv row layout (1536 bf16): q_h at h*128, k_h at 512+h*128, v_h at 1024+h*128.
// ---------------------------------------------------------------------------
__global__ __launch_bounds__(256) void flash_attn(const unsigned short* __restrict__ qkv,
                                                  float* __restrict__ o) {
  __shared__ float Qs[64][132];
  __shared__ float Ks[64][132];
  __shared__ float Vs[64][132];
  __shared__ float Ps[64][68];
  const int b = blockIdx.z, h = blockIdx.y, q0 = blockIdx.x * 64;
  const int t = threadIdx.x, ty = t >> 4, tx = t & 15;

#pragma unroll
  for (int it = 0; it < 4; ++it) {
    int idx = t + it * 256, r = idx >> 4, c = (idx & 15) * 8;
    short8 v = *(const short8*)&qkv[((size_t)(b * SEQ + q0 + r)) * 1536 + h * HDIM + c];
#pragma unroll
    for (int e = 0; e < 8; ++e) Qs[r][c + e] = bf2f((unsigned short)v[e]);
  }

  float m_i[4], l_i[4], oa[4][8];
#pragma unroll
  for (int i = 0; i < 4; ++i) {
    m_i[i] = -1e30f; l_i[i] = 0.f;
#pragma unroll
    for (int c = 0; c < 8; ++c) oa[i][c] = 0.f;
  }
  const float scale = 0.08838834764831845f;  // 1/sqrt(128)

  for (int kt = 0; kt < 8; ++kt) {
#pragma unroll
    for (int it = 0; it < 4; ++it) {
      int idx = t + it * 256, r = idx >> 4, c = (idx & 15) * 8;
      size_t base = ((size_t)(b * SEQ + kt * 64 + r)) * 1536 + h * HDIM + c;
      short8 kv = *(const short8*)&qkv[base + 512];
      short8 vv = *(const short8*)&qkv[base + 1024];
#pragma unroll
      for (int e = 0; e < 8; ++e) {
        Ks[r][c + e] = bf2f((unsigned short)kv[e]);
        Vs[r][c + e] = bf2f((unsigned short)vv[e]);
      }
    }
    __syncthreads();

    // S = scale * Q @ K^T   (4x4 per thread)
    float s[4][4] = {};
    for (int d = 0; d < 128; d += 4) {
      float4 qa[4], kb[4];
#pragma unroll
      for (int i = 0; i < 4; ++i) qa[i] = *(const float4*)&Qs[4 * ty + i][d];
#pragma unroll
      for (int j = 0; j < 4; ++j) kb[j] = *(const float4*)&Ks[4 * tx + j][d];
#pragma unroll
      for (int i = 0; i < 4; ++i)
#pragma unroll
        for (int j = 0; j < 4; ++j)
          s[i][j] += qa[i].x * kb[j].x + qa[i].y * kb[j].y +
                     qa[i].z * kb[j].z + qa[i].w * kb[j].w;
    }
#pragma unroll
    for (int i = 0; i < 4; ++i)
#pragma unroll
      for (int j = 0; j < 4; ++j) s[i][j] *= scale;

    // online softmax (row 4*ty+i spread over 16-lane group tx)
#pragma unroll
    for (int i = 0; i < 4; ++i) {
      float mx = fmaxf(fmaxf(s[i][0], s[i][1]), fmaxf(s[i][2], s[i][3]));
      mx = fmaxf(mx, __shfl_xor(mx, 1));
      mx = fmaxf(mx, __shfl_xor(mx, 2));
      mx = fmaxf(mx, __shfl_xor(mx, 4));
      mx = fmaxf(mx, __shfl_xor(mx, 8));
      float mn = fmaxf(m_i[i], mx);
      float al = __expf(m_i[i] - mn);
      float p0 = __expf(s[i][0] - mn), p1 = __expf(s[i][1] - mn);
      float p2 = __expf(s[i][2] - mn), p3 = __expf(s[i][3] - mn);
      float rs = p0 + p1 + p2 + p3;
      rs += __shfl_xor(rs, 1);
      rs += __shfl_xor(rs, 2);
      rs += __shfl_xor(rs, 4);
      rs += __shfl_xor(rs, 8);
      l_i[i] = l_i[i] * al + rs;
      m_i[i] = mn;
#pragma unroll
      for (int c = 0; c < 8; ++c) oa[i][c] *= al;
      Ps[4 * ty + i][4 * tx + 0] = p0;
      Ps[4 * ty + i][4 * tx + 1] = p1;
      Ps[4 * ty + i][4 * tx + 2] = p2;
      Ps[4 * ty + i][4 * tx + 3] = p3;
    }
    __syncthreads();

    // O += P @ V   (rows 4*ty+i, cols 8*tx..8*tx+7)
    for (int j0 = 0; j0 < 64; j0 += 4) {
      float4 pa[4];
#pragma unroll
      for (int i = 0; i < 4; ++i) pa[i] = *(const float4*)&Ps[4 * ty + i][j0];
#pragma unroll
      for (int jj = 0; jj < 4; ++jj) {
        float4 v0 = *(const float4*)&Vs[j0 + jj][8 * tx];
        float4 v1 = *(const float4*)&Vs[j0 + jj][8 * tx + 4];
#pragma unroll
        for (int i = 0; i < 4; ++i) {
          float p = ((float*)&pa[i])[jj];
          oa[i][0] += p * v0.x; oa[i][1] += p * v0.y;
          oa[i][2] += p * v0.z; oa[i][3] += p * v0.w;
          oa[i][4] += p * v1.x; oa[i][5] += p * v1.y;
          oa[i][6] += p * v1.z; oa[i][7] += p * v1.w;
        }
      }
    }
    __syncthreads();
  }

#pragma unroll
  for (int i = 0; i < 4; ++i) {
    float inv = 1.0f / l_i[i];
    size_t row = (size_t)(b * SEQ + q0 + 4 * ty + i);
    float4 r0, r1;
    r0.x = oa[i][0] * inv; r0.y = oa[i][1] * inv;
    r0.z = oa[i][2] * inv; r0.w = oa[i][3] * inv;
    r1.x = oa[i][4] * inv; r1.y = oa[i][5] * inv;
    r1.z = oa[i][6] * inv; r1.w = oa[i][7] * inv;
    *(float4*)&o[row * DMODEL + h * HDIM + 8 * tx] = r0;
    *(float4*)&o[row * DMODEL + h * HDIM + 8 * tx + 4] = r1;
  }
}

// ---------------------------------------------------------------------------
// y[row] = LN(x[row] + r[row]) * g + b     (row length 512, 1 block per row)
// ---------------------------------------------------------------------------
__global__ __launch_bounds__(256) void add_ln(const float* __restrict__ x,
                                              const float* __restrict__ r,
                                              const float* __restrict__ g,
                                              const float* __restrict__ beta,
                                              float* __restrict__ y) {
  const int row = blockIdx.x, t = threadIdx.x;
  const float* xr = x + (size_t)row * DMODEL;
  const float* rr = r + (size_t)row * DMODEL;
  float a0 = xr[t] + rr[t];
  float a1 = xr[t + 256] + rr[t + 256];
  float sum = a0 + a1, sq = a0 * a0 + a1 * a1;
#pragma unroll
  for (int m = 1; m < 64; m <<= 1) {
    sum += __shfl_xor(sum, m);
    sq += __shfl_xor(sq, m);
  }
  __shared__ float ssum[4], ssq[4];
  const int w = t >> 6;
  if ((t & 63) == 0) { ssum[w] = sum; ssq[w] = sq; }
  __syncthreads();
  sum = ssum[0] + ssum[1] + ssum[2] + ssum[3];
  sq = ssq[0] + ssq[1] + ssq[2] + ssq[3];
  const float mean = sum * (1.0f / DMODEL);
  const float var = sq * (1.0f / DMODEL) - mean * mean;
  const float rinv = rsqrtf(var + 1e-5f);
  float* yr = y + (size_t)row * DMODEL;
  yr[t] = (a0 - mean) * rinv * g[t] + beta[t];
  yr[t + 256] = (a1 - mean) * rinv * g[t + 256] + beta[t + 256];
}

// ---------------------------------------------------------------------------
// Masked mean-pool over prefix + 2-class linear head. 1 block per batch item.
// ---------------------------------------------------------------------------
__global__ __launch_bounds__(256) void pool_cls(const float* __restrict__ x,
                                                const int* __restrict__ mask,
                                                const float* __restrict__ wc,
                                                const float* __restrict__ bc,
                                                float* __restrict__ out) {
  const int b = blockIdx.x, t = threadIdx.x;
  float acc0 = 0.f, acc1 = 0.f;
  float cnt = 0.f;
  for (int s = 0; s < SEQ; ++s) {
    int m = mask[b * SEQ + s];  // prefix-ones: uniform across block
    if (m) {
      const float* xr = x + ((size_t)(b * SEQ + s)) * DMODEL;
      acc0 += xr[t];
      acc1 += xr[t + 256];
      cnt += 1.f;
    }
  }
  const float inv = 1.0f / cnt;
  const float p0 = acc0 * inv, p1 = acc1 * inv;
  float l0 = p0 * wc[t] + p1 * wc[t + 256];
  float l1 = p0 * wc[DMODEL + t] + p1 * wc[DMODEL + t + 256];
#pragma unroll
  for (int m = 1; m < 64; m <<= 1) {
    l0 += __shfl_xor(l0, m);
    l1 += __shfl_xor(l1, m);
  }
  __shared__ float r0s[4], r1s[4];
  const int w = t >> 6;
  if ((t & 63) == 0) { r0s[w] = l0; r1s[w] = l1; }
  __syncthreads();
  if (t == 0) {
    out[b * 2 + 0] = r0s[0] + r0s[1] + r0s[2] + r0s[3] + bc[0];
    out[b * 2 + 1] = r1s[0] + r1s[1] + r1s[2] + r1s[3] + bc[1];
  }
}

// ---------------------------------------------------------------------------
extern "C" void kernel_launch(void* const* d_in, const int* in_sizes, int n_in,
                              void* d_out, int out_size, void* d_ws, size_t ws_size,
                              hipStream_t stream) {
  (void)in_sizes; (void)n_in; (void)out_size; (void)ws_size;
  const float* vf    = (const float*)d_in[0];
  const int*   mask  = (const int*)d_in[1];
  const float* w_img = (const float*)d_in[2];
  const float* b_img = (const float*)d_in[3];
  const float* in_w  = (const float*)d_in[4];
  const float* in_b  = (const float*)d_in[5];
  const float* out_w = (const float*)d_in[6];
  const float* out_b = (const float*)d_in[7];
  const float* ln1_g = (const float*)d_in[8];
  const float* ln1_b = (const float*)d_in[9];
  const float* w1    = (const float*)d_in[10];
  const float* b1    = (const float*)d_in[11];
  const float* w2    = (const float*)d_in[12];
  const float* b2    = (const float*)d_in[13];
  const float* ln2_g = (const float*)d_in[14];
  const float* ln2_b = (const float*)d_in[15];
  const float* w_cls = (const float*)d_in[16];
  const float* b_cls = (const float*)d_in[17];
  float* out = (float*)d_out;

  // Workspace layout (360 MB total), live ranges verified:
  //   X   f32 [0,64)    QKV bf16 [64,160)   O f32 [160,224)   P f32 [224,288)
  //   X1  f32 [64,128)  (QKV dead after attn)
  //   HH  bf16 [160,288) (O dead after out-proj, P dead after ln1)
  //   Fo  f32 [288,352)  X2 f32 [0,64) (X dead after ln1)
  //   bf16 weights [352,360)
  char* ws = (char*)d_ws;
  const size_t MB = 1ull << 20;
  float*          X   = (float*)(ws + 0 * MB);
  unsigned short* QKV = (unsigned short*)(ws + 64 * MB);
  float*          O   = (float*)(ws + 160 * MB);
  float*          P   = (float*)(ws + 224 * MB);
  float*          X1  = (float*)(ws + 64 * MB);
  unsigned short* HH  = (unsigned short*)(ws + 160 * MB);
  float*          Fo  = (float*)(ws + 288 * MB);
  float*          X2  = (float*)(ws + 0 * MB);
  unsigned short* wb  = (unsigned short*)(ws + 352 * MB);
  unsigned short* wb_img = wb;                       // 512*768
  unsigned short* wb_in  = wb_img + 512 * 768;       // 1536*512
  unsigned short* wb_out = wb_in + 1536 * 512;       // 512*512
  unsigned short* wb_1   = wb_out + 512 * 512;       // 2048*512
  unsigned short* wb_2   = wb_1 + 2048 * 512;        // 512*2048

  dim3 blk(256);
  cast_bf16<<<dim3(512 * 768 / 1024), blk, 0, stream>>>(w_img, wb_img, 512 * 768);
  cast_bf16<<<dim3(1536 * 512 / 1024), blk, 0, stream>>>(in_w, wb_in, 1536 * 512);
  cast_bf16<<<dim3(512 * 512 / 1024), blk, 0, stream>>>(out_w, wb_out, 512 * 512);
  cast_bf16<<<dim3(2048 * 512 / 1024), blk, 0, stream>>>(w1, wb_1, 2048 * 512);
  cast_bf16<<<dim3(512 * 2048 / 1024), blk, 0, stream>>>(w2, wb_2, 512 * 2048);

  // X = relu(vf @ w_img^T + b_img)            [32768,768]x[512,768]
  gemm_mfma<1, 0, 0><<<dim3(DMODEL / 128, ROWS / 128), blk, 0, stream>>>(
      vf, wb_img, b_img, X, ROWS, DMODEL, D_INF);
  // QKV(bf16) = X @ in_w^T + in_b             [32768,512]x[1536,512]
  gemm_mfma<0, 1, 0><<<dim3(3 * DMODEL / 128, ROWS / 128), blk, 0, stream>>>(
      X, wb_in, in_b, QKV, ROWS, 3 * DMODEL, DMODEL);
  flash_attn<<<dim3(SEQ / 64, NHEAD, BATCH), blk, 0, stream>>>(QKV, O);
  // P = O @ out_w^T + out_b                   [32768,512]x[512,512]
  gemm_mfma<0, 0, 0><<<dim3(DMODEL / 128, ROWS / 128), blk, 0, stream>>>(
      O, wb_out, out_b, P, ROWS, DMODEL, DMODEL);
  add_ln<<<dim3(ROWS), blk, 0, stream>>>(X, P, ln1_g, ln1_b, X1);
  // HH(bf16) = relu(X1 @ w1^T + b1)           [32768,512]x[2048,512]
  gemm_mfma<1, 1, 0><<<dim3(FFDIM / 128, ROWS / 128), blk, 0, stream>>>(
      X1, wb_1, b1, HH, ROWS, FFDIM, DMODEL);
  // Fo = HH @ w2^T + b2                       [32768,2048]x[512,2048]
  gemm_mfma<0, 0, 1><<<dim3(DMODEL / 128, ROWS / 128), blk, 0, stream>>>(
      HH, wb_2, b2, Fo, ROWS, DMODEL, FFDIM);
  add_ln<<<dim3(ROWS), blk, 0, stream>>>(X1, Fo, ln2_g, ln2_b, X2);
  pool_cls<<<dim3(BATCH), blk, 0, stream>>>(X2, mask, w_cls, b_cls, out);
}

// Round 5
// 1005.451 us; speedup vs baseline: 1.5961x; 1.5961x over previous
//
#include <hip/hip_runtime.h>
#include <hip/hip_bf16.h>
#include <math.h>

// Problem constants (fixed by reference)
#define D_INF 768
#define DMODEL 512
#define NHEAD 4
#define HDIM 128
#define FFDIM 2048
#define BATCH 64
#define SEQ 512
#define ROWS (BATCH * SEQ)  // 32768

typedef __attribute__((ext_vector_type(8))) short short8;
typedef __attribute__((ext_vector_type(4))) short short4v;
typedef __attribute__((ext_vector_type(4))) float f32x4;

__device__ inline unsigned short f2bf(float f) {  // RNE fp32->bf16 (finite inputs)
  unsigned int u = __float_as_uint(f);
  return (unsigned short)((u + 0x7fffu + ((u >> 16) & 1u)) >> 16);
}
__device__ inline float bf2f(unsigned short h) {
  return __uint_as_float(((unsigned int)h) << 16);
}

// ---------------------------------------------------------------------------
// fp32 -> bf16 cast (weights, once per launch)
// ---------------------------------------------------------------------------
__global__ __launch_bounds__(256) void cast_bf16(const float* __restrict__ src,
                                                 unsigned short* __restrict__ dst,
                                                 int n) {
  int i = (blockIdx.x * 256 + threadIdx.x) * 4;
  if (i < n) {
    float4 v = *(const float4*)&src[i];
    short4v s;
    s.x = (short)f2bf(v.x); s.y = (short)f2bf(v.y);
    s.z = (short)f2bf(v.z); s.w = (short)f2bf(v.w);
    *(short4v*)&dst[i] = s;
  }
}

// ---------------------------------------------------------------------------
// MFMA bf16 GEMM:  C[M,N] = act(A[M,K] @ W[N,K]^T + bias[N]), fp32 accumulate.
// 128x128 tile, BK=32, 256 threads = 4 waves (2x2), 4x4 16x16x32 frags/wave.
// Validated in round 2 (absmax 3.9e-3 green).
// ---------------------------------------------------------------------------
template <int RELU, int OBF, int ABF>
__global__ __launch_bounds__(256) void gemm_mfma(const void* __restrict__ Av,
                                                 const unsigned short* __restrict__ W,
                                                 const float* __restrict__ bias,
                                                 void* __restrict__ Cv,
                                                 int M, int N, int K) {
  __shared__ __align__(16) short As[128][32];  // [m][k] bf16
  __shared__ __align__(16) short Ws[128][32];  // [n][k] bf16
  const int t = threadIdx.x;
  const int m0 = blockIdx.y * 128, n0 = blockIdx.x * 128;
  const int wid = t >> 6, lane = t & 63;
  const int wr = wid >> 1, wc = wid & 1;
  const int l15 = lane & 15, k8 = lane >> 4;

  f32x4 acc[4][4];
#pragma unroll
  for (int i = 0; i < 4; ++i)
#pragma unroll
    for (int j = 0; j < 4; ++j) acc[i][j] = (f32x4)0.0f;

  for (int kt = 0; kt < K; kt += 32) {
    __syncthreads();
    if (ABF) {
      const unsigned short* A = (const unsigned short*)Av;
#pragma unroll
      for (int i = 0; i < 2; ++i) {
        int g = t + i * 256;
        int r = g >> 2, f = g & 3;
        short8 v = *(const short8*)(A + (size_t)(m0 + r) * K + kt + f * 8);
        *(short8*)&As[r][f * 8] = v;
      }
    } else {
      const float* A = (const float*)Av;
#pragma unroll
      for (int i = 0; i < 4; ++i) {
        int g = t + i * 256;
        int r = g >> 3, f = g & 7;
        float4 v = *(const float4*)(A + (size_t)(m0 + r) * K + kt + f * 4);
        short4v s;
        s.x = (short)f2bf(v.x); s.y = (short)f2bf(v.y);
        s.z = (short)f2bf(v.z); s.w = (short)f2bf(v.w);
        *(short4v*)&As[r][f * 4] = s;
      }
    }
#pragma unroll
    for (int i = 0; i < 2; ++i) {
      int g = t + i * 256;
      int r = g >> 2, f = g & 3;
      short8 v = *(const short8*)(W + (size_t)(n0 + r) * K + kt + f * 8);
      *(short8*)&Ws[r][f * 8] = v;
    }
    __syncthreads();

    short8 af[4], bg[4];
#pragma unroll
    for (int i = 0; i < 4; ++i)
      af[i] = *(const short8*)&As[wr * 64 + i * 16 + l15][k8 * 8];
#pragma unroll
    for (int j = 0; j < 4; ++j)
      bg[j] = *(const short8*)&Ws[wc * 64 + j * 16 + l15][k8 * 8];
#pragma unroll
    for (int i = 0; i < 4; ++i)
#pragma unroll
      for (int j = 0; j < 4; ++j)
        acc[i][j] = __builtin_amdgcn_mfma_f32_16x16x32_bf16(af[i], bg[j],
                                                            acc[i][j], 0, 0, 0);
  }

#pragma unroll
  for (int j = 0; j < 4; ++j) {
    int col = n0 + wc * 64 + j * 16 + l15;
    float bv = bias[col];
#pragma unroll
    for (int i = 0; i < 4; ++i) {
      int rbase = m0 + wr * 64 + i * 16 + k8 * 4;
#pragma unroll
      for (int r = 0; r < 4; ++r) {
        float v = acc[i][j][r] + bv;
        if (RELU) v = fmaxf(v, 0.f);
        if (OBF)
          ((unsigned short*)Cv)[(size_t)(rbase + r) * N + col] = f2bf(v);
        else
          ((float*)Cv)[(size_t)(rbase + r) * N + col] = v;
      }
    }
  }
}

// ---------------------------------------------------------------------------
// V transpose: QKV[row][1024 + h*128 + d] -> Vt[(h*128+d)][row]
// Grid (S/64, H, B), 256 threads. Chunk-XOR-swizzled LDS tile.
// ---------------------------------------------------------------------------
__global__ __launch_bounds__(256) void transpose_v(const unsigned short* __restrict__ qkv,
                                                   unsigned short* __restrict__ vt) {
  __shared__ __align__(16) unsigned short T[64][136];
  const int b = blockIdx.z, h = blockIdx.y, s0 = blockIdx.x * 64;
  const int t = threadIdx.x;
#pragma unroll
  for (int it = 0; it < 4; ++it) {
    int c = t + it * 256;
    int s = c >> 4, c8 = c & 15;
    short8 v = *(const short8*)(qkv + (size_t)(b * SEQ + s0 + s) * 1536 + 1024 +
                                h * HDIM + c8 * 8);
    int cs = c8 ^ (s >> 3);
    *(short8*)&T[s][cs * 8] = v;
  }
  __syncthreads();
#pragma unroll
  for (int it = 0; it < 4; ++it) {
    int c = t + it * 256;
    int d = c >> 3, s8 = c & 7;  // output row d (0..127), s-chunk (0..7)
    int j = d >> 3, o = d & 7;
    short8 v;
#pragma unroll
    for (int e = 0; e < 8; ++e) v[e] = (short)T[s8 * 8 + e][(j ^ s8) * 8 + o];
    *(short8*)(vt + (size_t)(h * HDIM + d) * ROWS + b * SEQ + s0 + s8 * 8) = v;
  }
}

// ---------------------------------------------------------------------------
// MFMA flash attention (swapped-operand structure).
// Grid (S/128, H, B), 512 threads = 8 waves; wave handles 16 q rows.
// Per kv-tile (64): S^T = mfma(K_frag, Q_frag) -> lane owns q-col l15;
// in-register online softmax (shfl_xor 16/32 across hi-groups); P bf16 via
// per-wave LDS; O^T = mfma(Vt_frag, P_frag). V pre-transposed in global.
// All LDS pitches padded: row strides 272/144/144 B => <=2-way conflicts.
// ---------------------------------------------------------------------------
__global__ __launch_bounds__(512) void flash_attn_mfma(
    const unsigned short* __restrict__ qkv, const unsigned short* __restrict__ vt,
    unsigned short* __restrict__ o) {
  __shared__ __align__(16) unsigned short Ks[64][136];   // [kv][d]
  __shared__ __align__(16) unsigned short Vs[128][72];   // [d][kv]
  __shared__ __align__(16) unsigned short Ps[8][16][72]; // per-wave [q][kv]
  const int b = blockIdx.z, h = blockIdx.y, q0 = blockIdx.x * 128;
  const int t = threadIdx.x, wid = t >> 6, lane = t & 63;
  const int l15 = lane & 15, hi = lane >> 4;
  const int qrow = q0 + wid * 16 + l15;  // this lane's q (= MFMA col)

  // Q B-fragments in registers: qf[ks][j] = Q[qrow][32*ks + 8*hi + j]
  short8 qf[4];
  {
    const unsigned short* qb =
        qkv + (size_t)(b * SEQ + qrow) * 1536 + h * HDIM + 8 * hi;
#pragma unroll
    for (int ks = 0; ks < 4; ++ks) qf[ks] = *(const short8*)(qb + 32 * ks);
  }

  f32x4 oacc[8];
#pragma unroll
  for (int jf = 0; jf < 8; ++jf) oacc[jf] = (f32x4)0.0f;
  float m_i = -1e30f, l_i = 0.f;
  const float scale = 0.08838834764831845f;  // 1/sqrt(128)

  for (int kt = 0; kt < 8; ++kt) {
    // ---- stage K rows and Vt rows (bf16) ----
#pragma unroll
    for (int it = 0; it < 2; ++it) {
      int c = t + it * 512;
      int r = c >> 4, c8 = c & 15;
      short8 v = *(const short8*)(qkv + (size_t)(b * SEQ + kt * 64 + r) * 1536 +
                                  512 + h * HDIM + c8 * 8);
      *(short8*)&Ks[r][c8 * 8] = v;
    }
#pragma unroll
    for (int it = 0; it < 2; ++it) {
      int c = t + it * 512;
      int d = c >> 3, c8 = c & 7;
      short8 v = *(const short8*)(vt + (size_t)(h * HDIM + d) * ROWS + b * SEQ +
                                  kt * 64 + c8 * 8);
      *(short8*)&Vs[d][c8 * 8] = v;
    }
    __syncthreads();

    // ---- S^T[kv][q] = K @ Q^T ----
    f32x4 st[4];
#pragma unroll
    for (int i = 0; i < 4; ++i) st[i] = (f32x4)0.0f;
#pragma unroll
    for (int ks = 0; ks < 4; ++ks)
#pragma unroll
      for (int i = 0; i < 4; ++i) {
        short8 kf = *(const short8*)&Ks[i * 16 + l15][32 * ks + 8 * hi];
        st[i] = __builtin_amdgcn_mfma_f32_16x16x32_bf16(kf, qf[ks], st[i], 0, 0, 0);
      }

    // ---- online softmax over this tile (lane owns q-col; kv = 16i+4hi+r) ----
    float p[16];
    float pmax = -1e30f;
#pragma unroll
    for (int i = 0; i < 4; ++i)
#pragma unroll
      for (int r = 0; r < 4; ++r) {
        float sv = st[i][r] * scale;
        p[i * 4 + r] = sv;
        pmax = fmaxf(pmax, sv);
      }
    pmax = fmaxf(pmax, __shfl_xor(pmax, 16));
    pmax = fmaxf(pmax, __shfl_xor(pmax, 32));
    float mn = fmaxf(m_i, pmax);
    float al = __expf(m_i - mn);
    float rsum = 0.f;
#pragma unroll
    for (int e = 0; e < 16; ++e) {
      p[e] = __expf(p[e] - mn);
      rsum += p[e];
    }
    rsum += __shfl_xor(rsum, 16);
    rsum += __shfl_xor(rsum, 32);
    l_i = l_i * al + rsum;
    m_i = mn;
#pragma unroll
    for (int jf = 0; jf < 8; ++jf) oacc[jf] *= al;

    // ---- P -> bf16 in per-wave LDS: Ps[wid][q=l15][kv] ----
#pragma unroll
    for (int i = 0; i < 4; ++i) {
      uint2 u;
      u.x = (unsigned int)f2bf(p[i * 4 + 0]) | ((unsigned int)f2bf(p[i * 4 + 1]) << 16);
      u.y = (unsigned int)f2bf(p[i * 4 + 2]) | ((unsigned int)f2bf(p[i * 4 + 3]) << 16);
      *(uint2*)&Ps[wid][l15][16 * i + 4 * hi] = u;
    }

    // ---- O^T[d][q] += Vt @ P^T ----
#pragma unroll
    for (int ks2 = 0; ks2 < 2; ++ks2) {
      short8 pf = *(const short8*)&Ps[wid][l15][32 * ks2 + 8 * hi];
#pragma unroll
      for (int jf = 0; jf < 8; ++jf) {
        short8 vf = *(const short8*)&Vs[jf * 16 + l15][32 * ks2 + 8 * hi];
        oacc[jf] = __builtin_amdgcn_mfma_f32_16x16x32_bf16(vf, pf, oacc[jf], 0, 0, 0);
      }
    }
    __syncthreads();
  }

  // ---- normalize, store O as bf16 [row][dmodel] ----
  const float inv = 1.0f / l_i;
  unsigned short* ob = o + (size_t)(b * SEQ + qrow) * DMODEL + h * HDIM;
#pragma unroll
  for (int jf = 0; jf < 8; ++jf) {
    uint2 u;
    u.x = (unsigned int)f2bf(oacc[jf][0] * inv) |
          ((unsigned int)f2bf(oacc[jf][1] * inv) << 16);
    u.y = (unsigned int)f2bf(oacc[jf][2] * inv) |
          ((unsigned int)f2bf(oacc[jf][3] * inv) << 16);
    *(uint2*)(ob + 16 * jf + 4 * hi) = u;
  }
}

// ---------------------------------------------------------------------------
// y[row] = LN(x[row] + r[row]) * g + b     (row length 512, 1 block per row)
// ---------------------------------------------------------------------------
__global__ __launch_bounds__(256) void add_ln(const float* __restrict__ x,
                                              const float* __restrict__ r,
                                              const float* __restrict__ g,
                                              const float* __restrict__ beta,
                                              float* __restrict__ y) {
  const int row = blockIdx.x, t = threadIdx.x;
  const float* xr = x + (size_t)row * DMODEL;
  const float* rr = r + (size_t)row * DMODEL;
  float a0 = xr[t] + rr[t];
  float a1 = xr[t + 256] + rr[t + 256];
  float sum = a0 + a1, sq = a0 * a0 + a1 * a1;
#pragma unroll
  for (int m = 1; m < 64; m <<= 1) {
    sum += __shfl_xor(sum, m);
    sq += __shfl_xor(sq, m);
  }
  __shared__ float ssum[4], ssq[4];
  const int w = t >> 6;
  if ((t & 63) == 0) { ssum[w] = sum; ssq[w] = sq; }
  __syncthreads();
  sum = ssum[0] + ssum[1] + ssum[2] + ssum[3];
  sq = ssq[0] + ssq[1] + ssq[2] + ssq[3];
  const float mean = sum * (1.0f / DMODEL);
  const float var = sq * (1.0f / DMODEL) - mean * mean;
  const float rinv = rsqrtf(var + 1e-5f);
  float* yr = y + (size_t)row * DMODEL;
  yr[t] = (a0 - mean) * rinv * g[t] + beta[t];
  yr[t + 256] = (a1 - mean) * rinv * g[t + 256] + beta[t + 256];
}

// ---------------------------------------------------------------------------
// Masked mean-pool over prefix + 2-class linear head. 1 block per batch item.
// ---------------------------------------------------------------------------
__global__ __launch_bounds__(256) void pool_cls(const float* __restrict__ x,
                                                const int* __restrict__ mask,
                                                const float* __restrict__ wc,
                                                const float* __restrict__ bc,
                                                float* __restrict__ out) {
  const int b = blockIdx.x, t = threadIdx.x;
  float acc0 = 0.f, acc1 = 0.f;
  float cnt = 0.f;
  for (int s = 0; s < SEQ; ++s) {
    int m = mask[b * SEQ + s];  // prefix-ones: uniform across block
    if (m) {
      const float* xr = x + ((size_t)(b * SEQ + s)) * DMODEL;
      acc0 += xr[t];
      acc1 += xr[t + 256];
      cnt += 1.f;
    }
  }
  const float inv = 1.0f / cnt;
  const float p0 = acc0 * inv, p1 = acc1 * inv;
  float l0 = p0 * wc[t] + p1 * wc[t + 256];
  float l1 = p0 * wc[DMODEL + t] + p1 * wc[DMODEL + t + 256];
#pragma unroll
  for (int m = 1; m < 64; m <<= 1) {
    l0 += __shfl_xor(l0, m);
    l1 += __shfl_xor(l1, m);
  }
  __shared__ float r0s[4], r1s[4];
  const int w = t >> 6;
  if ((t & 63) == 0) { r0s[w] = l0; r1s[w] = l1; }
  __syncthreads();
  if (t == 0) {
    out[b * 2 + 0] = r0s[0] + r0s[1] + r0s[2] + r0s[3] + bc[0];
    out[b * 2 + 1] = r1s[0] + r1s[1] + r1s[2] + r1s[3] + bc[1];
  }
}

// ---------------------------------------------------------------------------
extern "C" void kernel_launch(void* const* d_in, const int* in_sizes, int n_in,
                              void* d_out, int out_size, void* d_ws, size_t ws_size,
                              hipStream_t stream) {
  (void)in_sizes; (void)n_in; (void)out_size; (void)ws_size;
  const float* vf    = (const float*)d_in[0];
  const int*   mask  = (const int*)d_in[1];
  const float* w_img = (const float*)d_in[2];
  const float* b_img = (const float*)d_in[3];
  const float* in_w  = (const float*)d_in[4];
  const float* in_b  = (const float*)d_in[5];
  const float* out_w = (const float*)d_in[6];
  const float* out_b = (const float*)d_in[7];
  const float* ln1_g = (const float*)d_in[8];
  const float* ln1_b = (const float*)d_in[9];
  const float* w1    = (const float*)d_in[10];
  const float* b1    = (const float*)d_in[11];
  const float* w2    = (const float*)d_in[12];
  const float* b2    = (const float*)d_in[13];
  const float* ln2_g = (const float*)d_in[14];
  const float* ln2_b = (const float*)d_in[15];
  const float* w_cls = (const float*)d_in[16];
  const float* b_cls = (const float*)d_in[17];
  float* out = (float*)d_out;

  // Workspace (peak 359 MB; 360 MB proven available in round 2).
  char* ws = (char*)d_ws;
  const size_t MB = 1ull << 20;
  float*          X   = (float*)(ws + 0 * MB);
  unsigned short* QKV = (unsigned short*)(ws + 64 * MB);
  unsigned short* Vt  = (unsigned short*)(ws + 160 * MB);
  unsigned short* Obf = (unsigned short*)(ws + 192 * MB);
  float*          P   = (float*)(ws + 224 * MB);
  float*          X1  = (float*)(ws + 64 * MB);
  unsigned short* HH  = (unsigned short*)(ws + 128 * MB);
  float*          Fo  = (float*)(ws + 0 * MB);
  float*          X2  = (float*)(ws + 256 * MB);
  unsigned short* wb  = (unsigned short*)(ws + 352 * MB);
  unsigned short* wb_img = wb;                   // 512*768
  unsigned short* wb_in  = wb_img + 512 * 768;   // 1536*512
  unsigned short* wb_out = wb_in + 1536 * 512;   // 512*512
  unsigned short* wb_1   = wb_out + 512 * 512;   // 2048*512
  unsigned short* wb_2   = wb_1 + 2048 * 512;    // 512*2048

  dim3 blk(256);
  cast_bf16<<<dim3(512 * 768 / 1024), blk, 0, stream>>>(w_img, wb_img, 512 * 768);
  cast_bf16<<<dim3(1536 * 512 / 1024), blk, 0, stream>>>(in_w, wb_in, 1536 * 512);
  cast_bf16<<<dim3(512 * 512 / 1024), blk, 0, stream>>>(out_w, wb_out, 512 * 512);
  cast_bf16<<<dim3(2048 * 512 / 1024), blk, 0, stream>>>(w1, wb_1, 2048 * 512);
  cast_bf16<<<dim3(512 * 2048 / 1024), blk, 0, stream>>>(w2, wb_2, 512 * 2048);

  // X = relu(vf @ w_img^T + b_img)
  gemm_mfma<1, 0, 0><<<dim3(DMODEL / 128, ROWS / 128), blk, 0, stream>>>(
      vf, wb_img, b_img, X, ROWS, DMODEL, D_INF);
  // QKV(bf16) = X @ in_w^T + in_b
  gemm_mfma<0, 1, 0><<<dim3(3 * DMODEL / 128, ROWS / 128), blk, 0, stream>>>(
      X, wb_in, in_b, QKV, ROWS, 3 * DMODEL, DMODEL);
  transpose_v<<<dim3(SEQ / 64, NHEAD, BATCH), blk, 0, stream>>>(QKV, Vt);
  flash_attn_mfma<<<dim3(SEQ / 128, NHEAD, BATCH), dim3(512), 0, stream>>>(QKV, Vt, Obf);
  // P = Obf @ out_w^T + out_b   (bf16 A path)
  gemm_mfma<0, 0, 1><<<dim3(DMODEL / 128, ROWS / 128), blk, 0, stream>>>(
      Obf, wb_out, out_b, P, ROWS, DMODEL, DMODEL);
  add_ln<<<dim3(ROWS), blk, 0, stream>>>(X, P, ln1_g, ln1_b, X1);
  // HH(bf16) = relu(X1 @ w1^T + b1)
  gemm_mfma<1, 1, 0><<<dim3(FFDIM / 128, ROWS / 128), blk, 0, stream>>>(
      X1, wb_1, b1, HH, ROWS, FFDIM, DMODEL);
  // Fo = HH @ w2^T + b2
  gemm_mfma<0, 0, 1><<<dim3(DMODEL / 128, ROWS / 128), blk, 0, stream>>>(
      HH, wb_2, b2, Fo, ROWS, DMODEL, FFDIM);
  add_ln<<<dim3(ROWS), blk, 0, stream>>>(X1, Fo, ln2_g, ln2_b, X2);
  pool_cls<<<dim3(BATCH), blk, 0, stream>>>(X2, mask, w_cls, b_cls, out);
}

// Round 11
// 791.457 us; speedup vs baseline: 2.0277x; 1.2704x over previous
//
#include <hip/hip_runtime.h>
#include <hip/hip_bf16.h>
#include <math.h>

// Problem constants (fixed by reference)
#define D_INF 768
#define DMODEL 512
#define NHEAD 4
#define HDIM 128
#define FFDIM 2048
#define BATCH 64
#define SEQ 512
#define ROWS (BATCH * SEQ)  // 32768

typedef __attribute__((ext_vector_type(8))) short short8;
typedef __attribute__((ext_vector_type(4))) short short4v;
typedef __attribute__((ext_vector_type(4))) float f32x4;

__device__ inline unsigned short f2bf(float f) {  // RNE fp32->bf16 (finite inputs)
  unsigned int u = __float_as_uint(f);
  return (unsigned short)((u + 0x7fffu + ((u >> 16) & 1u)) >> 16);
}
__device__ inline float bf2f(unsigned short h) {
  return __uint_as_float(((unsigned int)h) << 16);
}

// Async global->LDS DMA, 16B per lane. LDS dest is linear in lane
// (wave-uniform base + lane*16) — guaranteed by callers (byte off = g*16).
// NOTE: builtin params are NON-const addrspace pointers (LLVM "vv*1v*3IUiIiIUi");
// C-style cast drops const + performs the flat->AS addrspacecast in one step.
#if defined(__has_builtin) && __has_builtin(__builtin_amdgcn_global_load_lds)
#define HAVE_GLOAD_LDS 1
__device__ inline void gload_lds16(const void* g, void* l) {
  __builtin_amdgcn_global_load_lds(
      (__attribute__((address_space(1))) void*)g,
      (__attribute__((address_space(3))) void*)l, 16, 0, 0);
}
#else
#define HAVE_GLOAD_LDS 0
__device__ inline void gload_lds16(const void* g, void* l) {  // fallback: VGPR path
  *(short8*)l = *(const short8*)g;
}
#endif

// ---------------------------------------------------------------------------
// fp32 -> bf16 cast (weights, once per launch)
// ---------------------------------------------------------------------------
__global__ __launch_bounds__(256) void cast_bf16(const float* __restrict__ src,
                                                 unsigned short* __restrict__ dst,
                                                 int n) {
  int i = (blockIdx.x * 256 + threadIdx.x) * 4;
  if (i < n) {
    float4 v = *(const float4*)&src[i];
    short4v s;
    s.x = (short)f2bf(v.x); s.y = (short)f2bf(v.y);
    s.z = (short)f2bf(v.z); s.w = (short)f2bf(v.w);
    *(short4v*)&dst[i] = s;
  }
}

// ---------------------------------------------------------------------------
// MFMA bf16 GEMM:  C[M,N] = act(A[M,K] @ W[N,K]^T + bias[N]), fp32 accumulate.
// 128x128 tile, BK=32, 256 threads = 4 waves (2x2), 4x4 16x16x32 frags/wave.
// W (always) and A (when ABF) staged via global_load_lds width-16 DMA.
// OBF: 0 = f32 out, 1 = bf16 out, 2 = f32 out + bf16 copy to Cv2.
// ---------------------------------------------------------------------------
template <int RELU, int OBF, int ABF>
__global__ __launch_bounds__(256) void gemm_mfma(const void* __restrict__ Av,
                                                 const unsigned short* __restrict__ W,
                                                 const float* __restrict__ bias,
                                                 void* __restrict__ Cv,
                                                 unsigned short* __restrict__ Cv2,
                                                 int M, int N, int K) {
  __shared__ __align__(16) short As[128][32];  // [m][k] bf16
  __shared__ __align__(16) short Ws[128][32];  // [n][k] bf16
  const int t = threadIdx.x;
  const int m0 = blockIdx.y * 128, n0 = blockIdx.x * 128;
  const int wid = t >> 6, lane = t & 63;
  const int wr = wid >> 1, wc = wid & 1;
  const int l15 = lane & 15, k8 = lane >> 4;

  f32x4 acc[4][4];
#pragma unroll
  for (int i = 0; i < 4; ++i)
#pragma unroll
    for (int j = 0; j < 4; ++j) acc[i][j] = (f32x4)0.0f;

  for (int kt = 0; kt < K; kt += 32) {
    __syncthreads();  // prior fragment reads done before overwrite
    // W tile -> LDS via DMA (thread t covers bytes [g*16, g*16+16))
#pragma unroll
    for (int i = 0; i < 2; ++i) {
      int g = t + i * 256;
      int r = g >> 2, f = g & 3;
      gload_lds16(W + (size_t)(n0 + r) * K + kt + f * 8, (short*)Ws + g * 8);
    }
    if (ABF) {
      const unsigned short* A = (const unsigned short*)Av;
#pragma unroll
      for (int i = 0; i < 2; ++i) {
        int g = t + i * 256;
        int r = g >> 2, f = g & 3;
        gload_lds16(A + (size_t)(m0 + r) * K + kt + f * 8, (short*)As + g * 8);
      }
    } else {
      const float* A = (const float*)Av;
#pragma unroll
      for (int i = 0; i < 4; ++i) {
        int g = t + i * 256;
        int r = g >> 3, f = g & 7;
        float4 v = *(const float4*)(A + (size_t)(m0 + r) * K + kt + f * 4);
        short4v s;
        s.x = (short)f2bf(v.x); s.y = (short)f2bf(v.y);
        s.z = (short)f2bf(v.z); s.w = (short)f2bf(v.w);
        *(short4v*)&As[r][f * 4] = s;
      }
    }
    __syncthreads();  // compiler drains vmcnt/lgkmcnt before s_barrier

    short8 af[4], bg[4];
#pragma unroll
    for (int i = 0; i < 4; ++i)
      af[i] = *(const short8*)&As[wr * 64 + i * 16 + l15][k8 * 8];
#pragma unroll
    for (int j = 0; j < 4; ++j)
      bg[j] = *(const short8*)&Ws[wc * 64 + j * 16 + l15][k8 * 8];
#pragma unroll
    for (int i = 0; i < 4; ++i)
#pragma unroll
      for (int j = 0; j < 4; ++j)
        acc[i][j] = __builtin_amdgcn_mfma_f32_16x16x32_bf16(af[i], bg[j],
                                                            acc[i][j], 0, 0, 0);
  }

#pragma unroll
  for (int j = 0; j < 4; ++j) {
    int col = n0 + wc * 64 + j * 16 + l15;
    float bv = bias[col];
#pragma unroll
    for (int i = 0; i < 4; ++i) {
      int rbase = m0 + wr * 64 + i * 16 + k8 * 4;
#pragma unroll
      for (int r = 0; r < 4; ++r) {
        float v = acc[i][j][r] + bv;
        if (RELU) v = fmaxf(v, 0.f);
        size_t idx = (size_t)(rbase + r) * N + col;
        if (OBF == 1) {
          ((unsigned short*)Cv)[idx] = f2bf(v);
        } else {
          ((float*)Cv)[idx] = v;
          if (OBF == 2) Cv2[idx] = f2bf(v);
        }
      }
    }
  }
}

// ---------------------------------------------------------------------------
// V transpose: QKV[row][1024 + h*128 + d] -> Vt[(h*128+d)][row]
// Grid (S/64, H, B), 256 threads. Chunk-XOR-swizzled LDS tile.
// ---------------------------------------------------------------------------
__global__ __launch_bounds__(256) void transpose_v(const unsigned short* __restrict__ qkv,
                                                   unsigned short* __restrict__ vt) {
  __shared__ __align__(16) unsigned short T[64][136];
  const int b = blockIdx.z, h = blockIdx.y, s0 = blockIdx.x * 64;
  const int t = threadIdx.x;
#pragma unroll
  for (int it = 0; it < 4; ++it) {
    int c = t + it * 256;
    int s = c >> 4, c8 = c & 15;
    short8 v = *(const short8*)(qkv + (size_t)(b * SEQ + s0 + s) * 1536 + 1024 +
                                h * HDIM + c8 * 8);
    int cs = c8 ^ (s >> 3);
    *(short8*)&T[s][cs * 8] = v;
  }
  __syncthreads();
#pragma unroll
  for (int it = 0; it < 4; ++it) {
    int c = t + it * 256;
    int d = c >> 3, s8 = c & 7;  // output row d (0..127), s-chunk (0..7)
    int j = d >> 3, o = d & 7;
    short8 v;
#pragma unroll
    for (int e = 0; e < 8; ++e) v[e] = (short)T[s8 * 8 + e][(j ^ s8) * 8 + o];
    *(short8*)(vt + (size_t)(h * HDIM + d) * ROWS + b * SEQ + s0 + s8 * 8) = v;
  }
}

// ---------------------------------------------------------------------------
// MFMA flash attention (swapped-operand structure). Validated round 5.
// Grid (S/128, H, B), 512 threads = 8 waves; wave handles 16 q rows.
// ---------------------------------------------------------------------------
__global__ __launch_bounds__(512) void flash_attn_mfma(
    const unsigned short* __restrict__ qkv, const unsigned short* __restrict__ vt,
    unsigned short* __restrict__ o) {
  __shared__ __align__(16) unsigned short Ks[64][136];   // [kv][d]
  __shared__ __align__(16) unsigned short Vs[128][72];   // [d][kv]
  __shared__ __align__(16) unsigned short Ps[8][16][72]; // per-wave [q][kv]
  const int b = blockIdx.z, h = blockIdx.y, q0 = blockIdx.x * 128;
  const int t = threadIdx.x, wid = t >> 6, lane = t & 63;
  const int l15 = lane & 15, hi = lane >> 4;
  const int qrow = q0 + wid * 16 + l15;  // this lane's q (= MFMA col)

  short8 qf[4];
  {
    const unsigned short* qb =
        qkv + (size_t)(b * SEQ + qrow) * 1536 + h * HDIM + 8 * hi;
#pragma unroll
    for (int ks = 0; ks < 4; ++ks) qf[ks] = *(const short8*)(qb + 32 * ks);
  }

  f32x4 oacc[8];
#pragma unroll
  for (int jf = 0; jf < 8; ++jf) oacc[jf] = (f32x4)0.0f;
  float m_i = -1e30f, l_i = 0.f;
  const float scale = 0.08838834764831845f;  // 1/sqrt(128)

  for (int kt = 0; kt < 8; ++kt) {
#pragma unroll
    for (int it = 0; it < 2; ++it) {
      int c = t + it * 512;
      int r = c >> 4, c8 = c & 15;
      short8 v = *(const short8*)(qkv + (size_t)(b * SEQ + kt * 64 + r) * 1536 +
                                  512 + h * HDIM + c8 * 8);
      *(short8*)&Ks[r][c8 * 8] = v;
    }
#pragma unroll
    for (int it = 0; it < 2; ++it) {
      int c = t + it * 512;
      int d = c >> 3, c8 = c & 7;
      short8 v = *(const short8*)(vt + (size_t)(h * HDIM + d) * ROWS + b * SEQ +
                                  kt * 64 + c8 * 8);
      *(short8*)&Vs[d][c8 * 8] = v;
    }
    __syncthreads();

    // S^T[kv][q] = K @ Q^T
    f32x4 st[4];
#pragma unroll
    for (int i = 0; i < 4; ++i) st[i] = (f32x4)0.0f;
#pragma unroll
    for (int ks = 0; ks < 4; ++ks)
#pragma unroll
      for (int i = 0; i < 4; ++i) {
        short8 kf = *(const short8*)&Ks[i * 16 + l15][32 * ks + 8 * hi];
        st[i] = __builtin_amdgcn_mfma_f32_16x16x32_bf16(kf, qf[ks], st[i], 0, 0, 0);
      }

    // online softmax (lane owns q-col; kv = 16i+4hi+r)
    float p[16];
    float pmax = -1e30f;
#pragma unroll
    for (int i = 0; i < 4; ++i)
#pragma unroll
      for (int r = 0; r < 4; ++r) {
        float sv = st[i][r] * scale;
        p[i * 4 + r] = sv;
        pmax = fmaxf(pmax, sv);
      }
    pmax = fmaxf(pmax, __shfl_xor(pmax, 16));
    pmax = fmaxf(pmax, __shfl_xor(pmax, 32));
    float mn = fmaxf(m_i, pmax);
    float al = __expf(m_i - mn);
    float rsum = 0.f;
#pragma unroll
    for (int e = 0; e < 16; ++e) {
      p[e] = __expf(p[e] - mn);
      rsum += p[e];
    }
    rsum += __shfl_xor(rsum, 16);
    rsum += __shfl_xor(rsum, 32);
    l_i = l_i * al + rsum;
    m_i = mn;
#pragma unroll
    for (int jf = 0; jf < 8; ++jf) oacc[jf] *= al;

    // P -> bf16 in per-wave LDS
#pragma unroll
    for (int i = 0; i < 4; ++i) {
      uint2 u;
      u.x = (unsigned int)f2bf(p[i * 4 + 0]) | ((unsigned int)f2bf(p[i * 4 + 1]) << 16);
      u.y = (unsigned int)f2bf(p[i * 4 + 2]) | ((unsigned int)f2bf(p[i * 4 + 3]) << 16);
      *(uint2*)&Ps[wid][l15][16 * i + 4 * hi] = u;
    }

    // O^T[d][q] += Vt @ P^T
#pragma unroll
    for (int ks2 = 0; ks2 < 2; ++ks2) {
      short8 pf = *(const short8*)&Ps[wid][l15][32 * ks2 + 8 * hi];
#pragma unroll
      for (int jf = 0; jf < 8; ++jf) {
        short8 vf = *(const short8*)&Vs[jf * 16 + l15][32 * ks2 + 8 * hi];
        oacc[jf] = __builtin_amdgcn_mfma_f32_16x16x32_bf16(vf, pf, oacc[jf], 0, 0, 0);
      }
    }
    __syncthreads();
  }

  const float inv = 1.0f / l_i;
  unsigned short* ob = o + (size_t)(b * SEQ + qrow) * DMODEL + h * HDIM;
#pragma unroll
  for (int jf = 0; jf < 8; ++jf) {
    uint2 u;
    u.x = (unsigned int)f2bf(oacc[jf][0] * inv) |
          ((unsigned int)f2bf(oacc[jf][1] * inv) << 16);
    u.y = (unsigned int)f2bf(oacc[jf][2] * inv) |
          ((unsigned int)f2bf(oacc[jf][3] * inv) << 16);
    *(uint2*)(ob + 16 * jf + 4 * hi) = u;
  }
}

// ---------------------------------------------------------------------------
// y[row] = LN(x[row] + r[row]) * g + b  (row 512, 1 block/row)
// Optionally also writes bf16 copy yb (feeds next GEMM's DMA-staged A).
// ---------------------------------------------------------------------------
__global__ __launch_bounds__(256) void add_ln(const float* __restrict__ x,
                                              const float* __restrict__ r,
                                              const float* __restrict__ g,
                                              const float* __restrict__ beta,
                                              float* __restrict__ y,
                                              unsigned short* __restrict__ yb) {
  const int row = blockIdx.x, t = threadIdx.x;
  const float* xr = x + (size_t)row * DMODEL;
  const float* rr = r + (size_t)row * DMODEL;
  float a0 = xr[t] + rr[t];
  float a1 = xr[t + 256] + rr[t + 256];
  float sum = a0 + a1, sq = a0 * a0 + a1 * a1;
#pragma unroll
  for (int m = 1; m < 64; m <<= 1) {
    sum += __shfl_xor(sum, m);
    sq += __shfl_xor(sq, m);
  }
  __shared__ float ssum[4], ssq[4];
  const int w = t >> 6;
  if ((t & 63) == 0) { ssum[w] = sum; ssq[w] = sq; }
  __syncthreads();
  sum = ssum[0] + ssum[1] + ssum[2] + ssum[3];
  sq = ssq[0] + ssq[1] + ssq[2] + ssq[3];
  const float mean = sum * (1.0f / DMODEL);
  const float var = sq * (1.0f / DMODEL) - mean * mean;
  const float rinv = rsqrtf(var + 1e-5f);
  float v0 = (a0 - mean) * rinv * g[t] + beta[t];
  float v1 = (a1 - mean) * rinv * g[t + 256] + beta[t + 256];
  float* yr = y + (size_t)row * DMODEL;
  yr[t] = v0;
  yr[t + 256] = v1;
  if (yb) {
    yb[(size_t)row * DMODEL + t] = f2bf(v0);
    yb[(size_t)row * DMODEL + t + 256] = f2bf(v1);
  }
}

// ---------------------------------------------------------------------------
// Pooling, parallelized (round-5 fix: pool_cls was latency-bound at 190 µs,
// 64 blocks / 1.3% occupancy / 1% HBM). Three stages.
// ---------------------------------------------------------------------------
__global__ __launch_bounds__(256) void zero_pool(float* __restrict__ pooled) {
  pooled[blockIdx.x * 256 + threadIdx.x] = 0.f;
}

__global__ __launch_bounds__(256) void pool_partial(const float* __restrict__ x,
                                                    const int* __restrict__ mask,
                                                    float* __restrict__ pooled) {
  const int b = blockIdx.x >> 4;          // batch
  const int s0 = (blockIdx.x & 15) * 32;  // chunk of 32 seq rows
  const int t = threadIdx.x;
  if (mask[b * SEQ + s0] == 0) return;  // prefix mask: whole chunk inactive (uniform)
  float a0 = 0.f, a1 = 0.f;
  for (int s = 0; s < 32; ++s) {
    int row = b * SEQ + s0 + s;
    if (mask[row]) {  // uniform across block
      const float* xr = x + (size_t)row * DMODEL;
      a0 += xr[t];
      a1 += xr[t + 256];
    }
  }
  atomicAdd(&pooled[b * DMODEL + t], a0);
  atomicAdd(&pooled[b * DMODEL + t + 256], a1);
}

__global__ __launch_bounds__(256) void cls_head(const float* __restrict__ pooled,
                                                const int* __restrict__ mask,
                                                const float* __restrict__ wc,
                                                const float* __restrict__ bc,
                                                float* __restrict__ out) {
  const int b = blockIdx.x, t = threadIdx.x;
  float c = (float)(mask[b * SEQ + t] + mask[b * SEQ + t + 256]);
#pragma unroll
  for (int m = 1; m < 64; m <<= 1) c += __shfl_xor(c, m);
  __shared__ float cs[4], r0s[4], r1s[4];
  const int w = t >> 6;
  if ((t & 63) == 0) cs[w] = c;
  __syncthreads();
  const float cnt = cs[0] + cs[1] + cs[2] + cs[3];
  const float inv = 1.0f / cnt;
  const float p0 = pooled[b * DMODEL + t] * inv;
  const float p1 = pooled[b * DMODEL + t + 256] * inv;
  float l0 = p0 * wc[t] + p1 * wc[t + 256];
  float l1 = p0 * wc[DMODEL + t] + p1 * wc[DMODEL + t + 256];
#pragma unroll
  for (int m = 1; m < 64; m <<= 1) {
    l0 += __shfl_xor(l0, m);
    l1 += __shfl_xor(l1, m);
  }
  if ((t & 63) == 0) { r0s[w] = l0; r1s[w] = l1; }
  __syncthreads();
  if (t == 0) {
    out[b * 2 + 0] = r0s[0] + r0s[1] + r0s[2] + r0s[3] + bc[0];
    out[b * 2 + 1] = r1s[0] + r1s[1] + r1s[2] + r1s[3] + bc[1];
  }
}

// ---------------------------------------------------------------------------
extern "C" void kernel_launch(void* const* d_in, const int* in_sizes, int n_in,
                              void* d_out, int out_size, void* d_ws, size_t ws_size,
                              hipStream_t stream) {
  (void)in_sizes; (void)n_in; (void)out_size; (void)ws_size;
  const float* vf    = (const float*)d_in[0];
  const int*   mask  = (const int*)d_in[1];
  const float* w_img = (const float*)d_in[2];
  const float* b_img = (const float*)d_in[3];
  const float* in_w  = (const float*)d_in[4];
  const float* in_b  = (const float*)d_in[5];
  const float* out_w = (const float*)d_in[6];
  const float* out_b = (const float*)d_in[7];
  const float* ln1_g = (const float*)d_in[8];
  const float* ln1_b = (const float*)d_in[9];
  const float* w1    = (const float*)d_in[10];
  const float* b1    = (const float*)d_in[11];
  const float* w2    = (const float*)d_in[12];
  const float* b2    = (const float*)d_in[13];
  const float* ln2_g = (const float*)d_in[14];
  const float* ln2_b = (const float*)d_in[15];
  const float* w_cls = (const float*)d_in[16];
  const float* b_cls = (const float*)d_in[17];
  float* out = (float*)d_out;

  // Workspace layout (peak 359.125 MB < 360 proven; live ranges audited r9):
  //   X    f32 [0,64)      dead after ln1          Xb  bf16 [64,96)  dead after QKV
  //   QKV  bf16 [96,192)   dead after flash        Vt  bf16 [192,224) dead after flash
  //   Obf  bf16 [224,256)  dead after out-proj     P   f32 [256,320) dead after ln1
  //   X1   f32 [64,128)    dead after ln2          X1b bf16 [128,160) dead after FFN1
  //   HH   bf16 [160,288)  dead after FFN2         Fo  f32 [0,64)
  //   X2   f32 [288,352)   wb [352,~358.75)        pooled [359,359.125)
  char* ws = (char*)d_ws;
  const size_t MB = 1ull << 20;
  float*          X   = (float*)(ws + 0 * MB);
  unsigned short* Xb  = (unsigned short*)(ws + 64 * MB);
  unsigned short* QKV = (unsigned short*)(ws + 96 * MB);
  unsigned short* Vt  = (unsigned short*)(ws + 192 * MB);
  unsigned short* Obf = (unsigned short*)(ws + 224 * MB);
  float*          P   = (float*)(ws + 256 * MB);
  float*          X1  = (float*)(ws + 64 * MB);
  unsigned short* X1b = (unsigned short*)(ws + 128 * MB);
  unsigned short* HH  = (unsigned short*)(ws + 160 * MB);
  float*          Fo  = (float*)(ws + 0 * MB);
  float*          X2  = (float*)(ws + 288 * MB);
  unsigned short* wb  = (unsigned short*)(ws + 352 * MB);
  unsigned short* wb_img = wb;                   // 512*768
  unsigned short* wb_in  = wb_img + 512 * 768;   // 1536*512
  unsigned short* wb_out = wb_in + 1536 * 512;   // 512*512
  unsigned short* wb_1   = wb_out + 512 * 512;   // 2048*512
  unsigned short* wb_2   = wb_1 + 2048 * 512;    // 512*2048
  float*          pooled = (float*)(ws + 359 * MB);  // [64][512] f32

  dim3 blk(256);
  cast_bf16<<<dim3(512 * 768 / 1024), blk, 0, stream>>>(w_img, wb_img, 512 * 768);
  cast_bf16<<<dim3(1536 * 512 / 1024), blk, 0, stream>>>(in_w, wb_in, 1536 * 512);
  cast_bf16<<<dim3(512 * 512 / 1024), blk, 0, stream>>>(out_w, wb_out, 512 * 512);
  cast_bf16<<<dim3(2048 * 512 / 1024), blk, 0, stream>>>(w1, wb_1, 2048 * 512);
  cast_bf16<<<dim3(512 * 2048 / 1024), blk, 0, stream>>>(w2, wb_2, 512 * 2048);
  zero_pool<<<dim3(BATCH * DMODEL / 256), blk, 0, stream>>>(pooled);

  // X,Xb = relu(vf @ w_img^T + b_img)   (fp32 A path; dual-output)
  gemm_mfma<1, 2, 0><<<dim3(DMODEL / 128, ROWS / 128), blk, 0, stream>>>(
      vf, wb_img, b_img, X, Xb, ROWS, DMODEL, D_INF);
  // QKV(bf16) = Xb @ in_w^T + in_b      (full-DMA staging)
  gemm_mfma<0, 1, 1><<<dim3(3 * DMODEL / 128, ROWS / 128), blk, 0, stream>>>(
      Xb, wb_in, in_b, QKV, nullptr, ROWS, 3 * DMODEL, DMODEL);
  transpose_v<<<dim3(SEQ / 64, NHEAD, BATCH), blk, 0, stream>>>(QKV, Vt);
  flash_attn_mfma<<<dim3(SEQ / 128, NHEAD, BATCH), dim3(512), 0, stream>>>(QKV, Vt, Obf);
  // P = Obf @ out_w^T + out_b           (full-DMA staging)
  gemm_mfma<0, 0, 1><<<dim3(DMODEL / 128, ROWS / 128), blk, 0, stream>>>(
      Obf, wb_out, out_b, P, nullptr, ROWS, DMODEL, DMODEL);
  add_ln<<<dim3(ROWS), blk, 0, stream>>>(X, P, ln1_g, ln1_b, X1, X1b);
  // HH(bf16) = relu(X1b @ w1^T + b1)    (full-DMA staging)
  gemm_mfma<1, 1, 1><<<dim3(FFDIM / 128, ROWS / 128), blk, 0, stream>>>(
      X1b, wb_1, b1, HH, nullptr, ROWS, FFDIM, DMODEL);
  // Fo = HH @ w2^T + b2                 (full-DMA staging)
  gemm_mfma<0, 0, 1><<<dim3(DMODEL / 128, ROWS / 128), blk, 0, stream>>>(
      HH, wb_2, b2, Fo, nullptr, ROWS, DMODEL, FFDIM);
  add_ln<<<dim3(ROWS), blk, 0, stream>>>(X1, Fo, ln2_g, ln2_b, X2, nullptr);
  pool_partial<<<dim3(BATCH * 16), blk, 0, stream>>>(X2, mask, pooled);
  cls_head<<<dim3(BATCH), blk, 0, stream>>>(pooled, mask, w_cls, b_cls, out);
}

// Round 12
// 776.392 us; speedup vs baseline: 2.0670x; 1.0194x over previous
//
#include <hip/hip_runtime.h>
#include <hip/hip_bf16.h>
#include <math.h>

// Problem constants (fixed by reference)
#define D_INF 768
#define DMODEL 512
#define NHEAD 4
#define HDIM 128
#define FFDIM 2048
#define BATCH 64
#define SEQ 512
#define ROWS (BATCH * SEQ)  // 32768

typedef __attribute__((ext_vector_type(8))) short short8;
typedef __attribute__((ext_vector_type(4))) short short4v;
typedef __attribute__((ext_vector_type(4))) float f32x4;

__device__ inline unsigned short f2bf(float f) {  // RNE fp32->bf16 (finite inputs)
  unsigned int u = __float_as_uint(f);
  return (unsigned short)((u + 0x7fffu + ((u >> 16) & 1u)) >> 16);
}
__device__ inline float bf2f(unsigned short h) {
  return __uint_as_float(((unsigned int)h) << 16);
}

// Async global->LDS DMA, 16B per lane. LDS dest is linear in lane
// (wave-uniform base + lane*16) — guaranteed by callers (byte off = g*16).
#if defined(__has_builtin) && __has_builtin(__builtin_amdgcn_global_load_lds)
__device__ inline void gload_lds16(const void* g, void* l) {
  __builtin_amdgcn_global_load_lds(
      (__attribute__((address_space(1))) void*)g,
      (__attribute__((address_space(3))) void*)l, 16, 0, 0);
}
#else
__device__ inline void gload_lds16(const void* g, void* l) {  // fallback: VGPR path
  *(short8*)l = *(const short8*)g;
}
#endif

// ---------------------------------------------------------------------------
// fp32 -> bf16 cast (weights, once per launch)
// ---------------------------------------------------------------------------
__global__ __launch_bounds__(256) void cast_bf16(const float* __restrict__ src,
                                                 unsigned short* __restrict__ dst,
                                                 int n) {
  int i = (blockIdx.x * 256 + threadIdx.x) * 4;
  if (i < n) {
    float4 v = *(const float4*)&src[i];
    short4v s;
    s.x = (short)f2bf(v.x); s.y = (short)f2bf(v.y);
    s.z = (short)f2bf(v.z); s.w = (short)f2bf(v.w);
    *(short4v*)&dst[i] = s;
  }
}

// ---------------------------------------------------------------------------
// MFMA bf16 GEMM:  C[M,N] = act(A[M,K] @ W[N,K]^T + bias[N]), fp32 accumulate.
// 128x128 tile, BK=32, 256 threads = 4 waves (2x2), 4x4 16x16x32 frags/wave.
// W (always) and A (when ABF) staged via global_load_lds width-16 DMA.
// Round-12: XCD-aware chunked block swizzle (T1). Round-11 FETCH on FFN2 was
// 270 MB = 2x ideal: the n-blocks sharing an A-row-panel were round-robined
// across non-coherent per-XCD L2s. Chunked remap (bijective: all grids %8==0)
// gives each XCD a contiguous n-fastest tile range -> A-panel fetched once.
// OBF: 0 = f32 out, 1 = bf16 out, 2 = f32 out + bf16 copy to Cv2.
// ---------------------------------------------------------------------------
template <int RELU, int OBF, int ABF>
__global__ __launch_bounds__(256) void gemm_mfma(const void* __restrict__ Av,
                                                 const unsigned short* __restrict__ W,
                                                 const float* __restrict__ bias,
                                                 void* __restrict__ Cv,
                                                 unsigned short* __restrict__ Cv2,
                                                 int M, int N, int K) {
  __shared__ __align__(16) short As[128][32];  // [m][k] bf16
  __shared__ __align__(16) short Ws[128][32];  // [n][k] bf16
  const int t = threadIdx.x;
  // XCD swizzle: hardware assigns original bid round-robin to 8 XCDs; remap
  // so XCD k executes logical tiles [k*cpx, (k+1)*cpx) — contiguous, n-fastest.
  const int nwg = (int)(gridDim.x * gridDim.y);
  const int bid = (int)(blockIdx.x + blockIdx.y * gridDim.x);
  const int cpx = nwg >> 3;
  const int swz = (bid & 7) * cpx + (bid >> 3);
  const int m0 = (swz / (int)gridDim.x) * 128;
  const int n0 = (swz % (int)gridDim.x) * 128;
  const int wid = t >> 6, lane = t & 63;
  const int wr = wid >> 1, wc = wid & 1;
  const int l15 = lane & 15, k8 = lane >> 4;

  f32x4 acc[4][4];
#pragma unroll
  for (int i = 0; i < 4; ++i)
#pragma unroll
    for (int j = 0; j < 4; ++j) acc[i][j] = (f32x4)0.0f;

  for (int kt = 0; kt < K; kt += 32) {
    __syncthreads();  // prior fragment reads done before overwrite
    // W tile -> LDS via DMA (thread t covers bytes [g*16, g*16+16))
#pragma unroll
    for (int i = 0; i < 2; ++i) {
      int g = t + i * 256;
      int r = g >> 2, f = g & 3;
      gload_lds16(W + (size_t)(n0 + r) * K + kt + f * 8, (short*)Ws + g * 8);
    }
    if (ABF) {
      const unsigned short* A = (const unsigned short*)Av;
#pragma unroll
      for (int i = 0; i < 2; ++i) {
        int g = t + i * 256;
        int r = g >> 2, f = g & 3;
        gload_lds16(A + (size_t)(m0 + r) * K + kt + f * 8, (short*)As + g * 8);
      }
    } else {
      const float* A = (const float*)Av;
#pragma unroll
      for (int i = 0; i < 4; ++i) {
        int g = t + i * 256;
        int r = g >> 3, f = g & 7;
        float4 v = *(const float4*)(A + (size_t)(m0 + r) * K + kt + f * 4);
        short4v s;
        s.x = (short)f2bf(v.x); s.y = (short)f2bf(v.y);
        s.z = (short)f2bf(v.z); s.w = (short)f2bf(v.w);
        *(short4v*)&As[r][f * 4] = s;
      }
    }
    __syncthreads();  // compiler drains vmcnt/lgkmcnt before s_barrier

    short8 af[4], bg[4];
#pragma unroll
    for (int i = 0; i < 4; ++i)
      af[i] = *(const short8*)&As[wr * 64 + i * 16 + l15][k8 * 8];
#pragma unroll
    for (int j = 0; j < 4; ++j)
      bg[j] = *(const short8*)&Ws[wc * 64 + j * 16 + l15][k8 * 8];
#pragma unroll
    for (int i = 0; i < 4; ++i)
#pragma unroll
      for (int j = 0; j < 4; ++j)
        acc[i][j] = __builtin_amdgcn_mfma_f32_16x16x32_bf16(af[i], bg[j],
                                                            acc[i][j], 0, 0, 0);
  }

#pragma unroll
  for (int j = 0; j < 4; ++j) {
    int col = n0 + wc * 64 + j * 16 + l15;
    float bv = bias[col];
#pragma unroll
    for (int i = 0; i < 4; ++i) {
      int rbase = m0 + wr * 64 + i * 16 + k8 * 4;
#pragma unroll
      for (int r = 0; r < 4; ++r) {
        float v = acc[i][j][r] + bv;
        if (RELU) v = fmaxf(v, 0.f);
        size_t idx = (size_t)(rbase + r) * N + col;
        if (OBF == 1) {
          ((unsigned short*)Cv)[idx] = f2bf(v);
        } else {
          ((float*)Cv)[idx] = v;
          if (OBF == 2) Cv2[idx] = f2bf(v);
        }
      }
    }
  }
}

// ---------------------------------------------------------------------------
// V transpose: QKV[row][1024 + h*128 + d] -> Vt[(h*128+d)][row]
// Grid (S/64, H, B), 256 threads. Chunk-XOR-swizzled LDS tile.
// ---------------------------------------------------------------------------
__global__ __launch_bounds__(256) void transpose_v(const unsigned short* __restrict__ qkv,
                                                   unsigned short* __restrict__ vt) {
  __shared__ __align__(16) unsigned short T[64][136];
  const int b = blockIdx.z, h = blockIdx.y, s0 = blockIdx.x * 64;
  const int t = threadIdx.x;
#pragma unroll
  for (int it = 0; it < 4; ++it) {
    int c = t + it * 256;
    int s = c >> 4, c8 = c & 15;
    short8 v = *(const short8*)(qkv + (size_t)(b * SEQ + s0 + s) * 1536 + 1024 +
                                h * HDIM + c8 * 8);
    int cs = c8 ^ (s >> 3);
    *(short8*)&T[s][cs * 8] = v;
  }
  __syncthreads();
#pragma unroll
  for (int it = 0; it < 4; ++it) {
    int c = t + it * 256;
    int d = c >> 3, s8 = c & 7;  // output row d (0..127), s-chunk (0..7)
    int j = d >> 3, o = d & 7;
    short8 v;
#pragma unroll
    for (int e = 0; e < 8; ++e) v[e] = (short)T[s8 * 8 + e][(j ^ s8) * 8 + o];
    *(short8*)(vt + (size_t)(h * HDIM + d) * ROWS + b * SEQ + s0 + s8 * 8) = v;
  }
}

// ---------------------------------------------------------------------------
// MFMA flash attention (swapped-operand structure). Validated round 5.
// Grid (S/128, H, B), 512 threads = 8 waves; wave handles 16 q rows.
// ---------------------------------------------------------------------------
__global__ __launch_bounds__(512) void flash_attn_mfma(
    const unsigned short* __restrict__ qkv, const unsigned short* __restrict__ vt,
    unsigned short* __restrict__ o) {
  __shared__ __align__(16) unsigned short Ks[64][136];   // [kv][d]
  __shared__ __align__(16) unsigned short Vs[128][72];   // [d][kv]
  __shared__ __align__(16) unsigned short Ps[8][16][72]; // per-wave [q][kv]
  const int b = blockIdx.z, h = blockIdx.y, q0 = blockIdx.x * 128;
  const int t = threadIdx.x, wid = t >> 6, lane = t & 63;
  const int l15 = lane & 15, hi = lane >> 4;
  const int qrow = q0 + wid * 16 + l15;  // this lane's q (= MFMA col)

  short8 qf[4];
  {
    const unsigned short* qb =
        qkv + (size_t)(b * SEQ + qrow) * 1536 + h * HDIM + 8 * hi;
#pragma unroll
    for (int ks = 0; ks < 4; ++ks) qf[ks] = *(const short8*)(qb + 32 * ks);
  }

  f32x4 oacc[8];
#pragma unroll
  for (int jf = 0; jf < 8; ++jf) oacc[jf] = (f32x4)0.0f;
  float m_i = -1e30f, l_i = 0.f;
  const float scale = 0.08838834764831845f;  // 1/sqrt(128)

  for (int kt = 0; kt < 8; ++kt) {
#pragma unroll
    for (int it = 0; it < 2; ++it) {
      int c = t + it * 512;
      int r = c >> 4, c8 = c & 15;
      short8 v = *(const short8*)(qkv + (size_t)(b * SEQ + kt * 64 + r) * 1536 +
                                  512 + h * HDIM + c8 * 8);
      *(short8*)&Ks[r][c8 * 8] = v;
    }
#pragma unroll
    for (int it = 0; it < 2; ++it) {
      int c = t + it * 512;
      int d = c >> 3, c8 = c & 7;
      short8 v = *(const short8*)(vt + (size_t)(h * HDIM + d) * ROWS + b * SEQ +
                                  kt * 64 + c8 * 8);
      *(short8*)&Vs[d][c8 * 8] = v;
    }
    __syncthreads();

    // S^T[kv][q] = K @ Q^T
    f32x4 st[4];
#pragma unroll
    for (int i = 0; i < 4; ++i) st[i] = (f32x4)0.0f;
#pragma unroll
    for (int ks = 0; ks < 4; ++ks)
#pragma unroll
      for (int i = 0; i < 4; ++i) {
        short8 kf = *(const short8*)&Ks[i * 16 + l15][32 * ks + 8 * hi];
        st[i] = __builtin_amdgcn_mfma_f32_16x16x32_bf16(kf, qf[ks], st[i], 0, 0, 0);
      }

    // online softmax (lane owns q-col; kv = 16i+4hi+r)
    float p[16];
    float pmax = -1e30f;
#pragma unroll
    for (int i = 0; i < 4; ++i)
#pragma unroll
      for (int r = 0; r < 4; ++r) {
        float sv = st[i][r] * scale;
        p[i * 4 + r] = sv;
        pmax = fmaxf(pmax, sv);
      }
    pmax = fmaxf(pmax, __shfl_xor(pmax, 16));
    pmax = fmaxf(pmax, __shfl_xor(pmax, 32));
    float mn = fmaxf(m_i, pmax);
    float al = __expf(m_i - mn);
    float rsum = 0.f;
#pragma unroll
    for (int e = 0; e < 16; ++e) {
      p[e] = __expf(p[e] - mn);
      rsum += p[e];
    }
    rsum += __shfl_xor(rsum, 16);
    rsum += __shfl_xor(rsum, 32);
    l_i = l_i * al + rsum;
    m_i = mn;
#pragma unroll
    for (int jf = 0; jf < 8; ++jf) oacc[jf] *= al;

    // P -> bf16 in per-wave LDS
#pragma unroll
    for (int i = 0; i < 4; ++i) {
      uint2 u;
      u.x = (unsigned int)f2bf(p[i * 4 + 0]) | ((unsigned int)f2bf(p[i * 4 + 1]) << 16);
      u.y = (unsigned int)f2bf(p[i * 4 + 2]) | ((unsigned int)f2bf(p[i * 4 + 3]) << 16);
      *(uint2*)&Ps[wid][l15][16 * i + 4 * hi] = u;
    }

    // O^T[d][q] += Vt @ P^T
#pragma unroll
    for (int ks2 = 0; ks2 < 2; ++ks2) {
      short8 pf = *(const short8*)&Ps[wid][l15][32 * ks2 + 8 * hi];
#pragma unroll
      for (int jf = 0; jf < 8; ++jf) {
        short8 vf = *(const short8*)&Vs[jf * 16 + l15][32 * ks2 + 8 * hi];
        oacc[jf] = __builtin_amdgcn_mfma_f32_16x16x32_bf16(vf, pf, oacc[jf], 0, 0, 0);
      }
    }
    __syncthreads();
  }

  const float inv = 1.0f / l_i;
  unsigned short* ob = o + (size_t)(b * SEQ + qrow) * DMODEL + h * HDIM;
#pragma unroll
  for (int jf = 0; jf < 8; ++jf) {
    uint2 u;
    u.x = (unsigned int)f2bf(oacc[jf][0] * inv) |
          ((unsigned int)f2bf(oacc[jf][1] * inv) << 16);
    u.y = (unsigned int)f2bf(oacc[jf][2] * inv) |
          ((unsigned int)f2bf(oacc[jf][3] * inv) << 16);
    *(uint2*)(ob + 16 * jf + 4 * hi) = u;
  }
}

// ---------------------------------------------------------------------------
// y[row] = LN(x[row] + r[row]) * g + b  (row 512, 1 block/row)
// Optionally also writes bf16 copy yb (feeds next GEMM's DMA-staged A).
// ---------------------------------------------------------------------------
__global__ __launch_bounds__(256) void add_ln(const float* __restrict__ x,
                                              const float* __restrict__ r,
                                              const float* __restrict__ g,
                                              const float* __restrict__ beta,
                                              float* __restrict__ y,
                                              unsigned short* __restrict__ yb) {
  const int row = blockIdx.x, t = threadIdx.x;
  const float* xr = x + (size_t)row * DMODEL;
  const float* rr = r + (size_t)row * DMODEL;
  float a0 = xr[t] + rr[t];
  float a1 = xr[t + 256] + rr[t + 256];
  float sum = a0 + a1, sq = a0 * a0 + a1 * a1;
#pragma unroll
  for (int m = 1; m < 64; m <<= 1) {
    sum += __shfl_xor(sum, m);
    sq += __shfl_xor(sq, m);
  }
  __shared__ float ssum[4], ssq[4];
  const int w = t >> 6;
  if ((t & 63) == 0) { ssum[w] = sum; ssq[w] = sq; }
  __syncthreads();
  sum = ssum[0] + ssum[1] + ssum[2] + ssum[3];
  sq = ssq[0] + ssq[1] + ssq[2] + ssq[3];
  const float mean = sum * (1.0f / DMODEL);
  const float var = sq * (1.0f / DMODEL) - mean * mean;
  const float rinv = rsqrtf(var + 1e-5f);
  float v0 = (a0 - mean) * rinv * g[t] + beta[t];
  float v1 = (a1 - mean) * rinv * g[t + 256] + beta[t + 256];
  float* yr = y + (size_t)row * DMODEL;
  yr[t] = v0;
  yr[t + 256] = v1;
  if (yb) {
    yb[(size_t)row * DMODEL + t] = f2bf(v0);
    yb[(size_t)row * DMODEL + t + 256] = f2bf(v1);
  }
}

// ---------------------------------------------------------------------------
// Pooling, parallelized (round-5 fix: pool_cls was latency-bound at 190 µs,
// 64 blocks / 1.3% occupancy / 1% HBM). Three stages.
// ---------------------------------------------------------------------------
__global__ __launch_bounds__(256) void zero_pool(float* __restrict__ pooled) {
  pooled[blockIdx.x * 256 + threadIdx.x] = 0.f;
}

__global__ __launch_bounds__(256) void pool_partial(const float* __restrict__ x,
                                                    const int* __restrict__ mask,
                                                    float* __restrict__ pooled) {
  const int b = blockIdx.x >> 4;          // batch
  const int s0 = (blockIdx.x & 15) * 32;  // chunk of 32 seq rows
  const int t = threadIdx.x;
  if (mask[b * SEQ + s0] == 0) return;  // prefix mask: whole chunk inactive (uniform)
  float a0 = 0.f, a1 = 0.f;
  for (int s = 0; s < 32; ++s) {
    int row = b * SEQ + s0 + s;
    if (mask[row]) {  // uniform across block
      const float* xr = x + (size_t)row * DMODEL;
      a0 += xr[t];
      a1 += xr[t + 256];
    }
  }
  atomicAdd(&pooled[b * DMODEL + t], a0);
  atomicAdd(&pooled[b * DMODEL + t + 256], a1);
}

__global__ __launch_bounds__(256) void cls_head(const float* __restrict__ pooled,
                                                const int* __restrict__ mask,
                                                const float* __restrict__ wc,
                                                const float* __restrict__ bc,
                                                float* __restrict__ out) {
  const int b = blockIdx.x, t = threadIdx.x;
  float c = (float)(mask[b * SEQ + t] + mask[b * SEQ + t + 256]);
#pragma unroll
  for (int m = 1; m < 64; m <<= 1) c += __shfl_xor(c, m);
  __shared__ float cs[4], r0s[4], r1s[4];
  const int w = t >> 6;
  if ((t & 63) == 0) cs[w] = c;
  __syncthreads();
  const float cnt = cs[0] + cs[1] + cs[2] + cs[3];
  const float inv = 1.0f / cnt;
  const float p0 = pooled[b * DMODEL + t] * inv;
  const float p1 = pooled[b * DMODEL + t + 256] * inv;
  float l0 = p0 * wc[t] + p1 * wc[t + 256];
  float l1 = p0 * wc[DMODEL + t] + p1 * wc[DMODEL + t + 256];
#pragma unroll
  for (int m = 1; m < 64; m <<= 1) {
    l0 += __shfl_xor(l0, m);
    l1 += __shfl_xor(l1, m);
  }
  if ((t & 63) == 0) { r0s[w] = l0; r1s[w] = l1; }
  __syncthreads();
  if (t == 0) {
    out[b * 2 + 0] = r0s[0] + r0s[1] + r0s[2] + r0s[3] + bc[0];
    out[b * 2 + 1] = r1s[0] + r1s[1] + r1s[2] + r1s[3] + bc[1];
  }
}

// ---------------------------------------------------------------------------
extern "C" void kernel_launch(void* const* d_in, const int* in_sizes, int n_in,
                              void* d_out, int out_size, void* d_ws, size_t ws_size,
                              hipStream_t stream) {
  (void)in_sizes; (void)n_in; (void)out_size; (void)ws_size;
  const float* vf    = (const float*)d_in[0];
  const int*   mask  = (const int*)d_in[1];
  const float* w_img = (const float*)d_in[2];
  const float* b_img = (const float*)d_in[3];
  const float* in_w  = (const float*)d_in[4];
  const float* in_b  = (const float*)d_in[5];
  const float* out_w = (const float*)d_in[6];
  const float* out_b = (const float*)d_in[7];
  const float* ln1_g = (const float*)d_in[8];
  const float* ln1_b = (const float*)d_in[9];
  const float* w1    = (const float*)d_in[10];
  const float* b1    = (const float*)d_in[11];
  const float* w2    = (const float*)d_in[12];
  const float* b2    = (const float*)d_in[13];
  const float* ln2_g = (const float*)d_in[14];
  const float* ln2_b = (const float*)d_in[15];
  const float* w_cls = (const float*)d_in[16];
  const float* b_cls = (const float*)d_in[17];
  float* out = (float*)d_out;

  // Workspace layout (peak 359.125 MB < 360 proven; live ranges audited r9):
  //   X    f32 [0,64)      dead after ln1          Xb  bf16 [64,96)  dead after QKV
  //   QKV  bf16 [96,192)   dead after flash        Vt  bf16 [192,224) dead after flash
  //   Obf  bf16 [224,256)  dead after out-proj     P   f32 [256,320) dead after ln1
  //   X1   f32 [64,128)    dead after ln2          X1b bf16 [128,160) dead after FFN1
  //   HH   bf16 [160,288)  dead after FFN2         Fo  f32 [0,64)
  //   X2   f32 [288,352)   wb [352,~358.75)        pooled [359,359.125)
  char* ws = (char*)d_ws;
  const size_t MB = 1ull << 20;
  float*          X   = (float*)(ws + 0 * MB);
  unsigned short* Xb  = (unsigned short*)(ws + 64 * MB);
  unsigned short* QKV = (unsigned short*)(ws + 96 * MB);
  unsigned short* Vt  = (unsigned short*)(ws + 192 * MB);
  unsigned short* Obf = (unsigned short*)(ws + 224 * MB);
  float*          P   = (float*)(ws + 256 * MB);
  float*          X1  = (float*)(ws + 64 * MB);
  unsigned short* X1b = (unsigned short*)(ws + 128 * MB);
  unsigned short* HH  = (unsigned short*)(ws + 160 * MB);
  float*          Fo  = (float*)(ws + 0 * MB);
  float*          X2  = (float*)(ws + 288 * MB);
  unsigned short* wb  = (unsigned short*)(ws + 352 * MB);
  unsigned short* wb_img = wb;                   // 512*768
  unsigned short* wb_in  = wb_img + 512 * 768;   // 1536*512
  unsigned short* wb_out = wb_in + 1536 * 512;   // 512*512
  unsigned short* wb_1   = wb_out + 512 * 512;   // 2048*512
  unsigned short* wb_2   = wb_1 + 2048 * 512;    // 512*2048
  float*          pooled = (float*)(ws + 359 * MB);  // [64][512] f32

  dim3 blk(256);
  cast_bf16<<<dim3(512 * 768 / 1024), blk, 0, stream>>>(w_img, wb_img, 512 * 768);
  cast_bf16<<<dim3(1536 * 512 / 1024), blk, 0, stream>>>(in_w, wb_in, 1536 * 512);
  cast_bf16<<<dim3(512 * 512 / 1024), blk, 0, stream>>>(out_w, wb_out, 512 * 512);
  cast_bf16<<<dim3(2048 * 512 / 1024), blk, 0, stream>>>(w1, wb_1, 2048 * 512);
  cast_bf16<<<dim3(512 * 2048 / 1024), blk, 0, stream>>>(w2, wb_2, 512 * 2048);
  zero_pool<<<dim3(BATCH * DMODEL / 256), blk, 0, stream>>>(pooled);

  // X,Xb = relu(vf @ w_img^T + b_img)   (fp32 A path; dual-output)
  gemm_mfma<1, 2, 0><<<dim3(DMODEL / 128, ROWS / 128), blk, 0, stream>>>(
      vf, wb_img, b_img, X, Xb, ROWS, DMODEL, D_INF);
  // QKV(bf16) = Xb @ in_w^T + in_b      (full-DMA staging)
  gemm_mfma<0, 1, 1><<<dim3(3 * DMODEL / 128, ROWS / 128), blk, 0, stream>>>(
      Xb, wb_in, in_b, QKV, nullptr, ROWS, 3 * DMODEL, DMODEL);
  transpose_v<<<dim3(SEQ / 64, NHEAD, BATCH), blk, 0, stream>>>(QKV, Vt);
  flash_attn_mfma<<<dim3(SEQ / 128, NHEAD, BATCH), dim3(512), 0, stream>>>(QKV, Vt, Obf);
  // P = Obf @ out_w^T + out_b           (full-DMA staging)
  gemm_mfma<0, 0, 1><<<dim3(DMODEL / 128, ROWS / 128), blk, 0, stream>>>(
      Obf, wb_out, out_b, P, nullptr, ROWS, DMODEL, DMODEL);
  add_ln<<<dim3(ROWS), blk, 0, stream>>>(X, P, ln1_g, ln1_b, X1, X1b);
  // HH(bf16) = relu(X1b @ w1^T + b1)    (full-DMA staging)
  gemm_mfma<1, 1, 1><<<dim3(FFDIM / 128, ROWS / 128), blk, 0, stream>>>(
      X1b, wb_1, b1, HH, nullptr, ROWS, FFDIM, DMODEL);
  // Fo = HH @ w2^T + b2                 (full-DMA staging)
  gemm_mfma<0, 0, 1><<<dim3(DMODEL / 128, ROWS / 128), blk, 0, stream>>>(
      HH, wb_2, b2, Fo, nullptr, ROWS, DMODEL, FFDIM);
  add_ln<<<dim3(ROWS), blk, 0, stream>>>(X1, Fo, ln2_g, ln2_b, X2, nullptr);
  pool_partial<<<dim3(BATCH * 16), blk, 0, stream>>>(X2, mask, pooled);
  cls_head<<<dim3(BATCH), blk, 0, stream>>>(pooled, mask, w_cls, b_cls, out);
}

// Round 14
// 771.199 us; speedup vs baseline: 2.0810x; 1.0067x over previous
//
#include <hip/hip_runtime.h>
#include <hip/hip_bf16.h>
#include <math.h>

// Problem constants (fixed by reference)
#define D_INF 768
#define DMODEL 512
#define NHEAD 4
#define HDIM 128
#define FFDIM 2048
#define BATCH 64
#define SEQ 512
#define ROWS (BATCH * SEQ)  // 32768

typedef __attribute__((ext_vector_type(8))) short short8;
typedef __attribute__((ext_vector_type(4))) short short4v;
typedef __attribute__((ext_vector_type(4))) float f32x4;

__device__ inline unsigned short f2bf(float f) {  // RNE fp32->bf16 (finite inputs)
  unsigned int u = __float_as_uint(f);
  return (unsigned short)((u + 0x7fffu + ((u >> 16) & 1u)) >> 16);
}
__device__ inline float bf2f(unsigned short h) {
  return __uint_as_float(((unsigned int)h) << 16);
}

// Async global->LDS DMA, 16B per lane. LDS dest is linear in lane
// (wave-uniform base + lane*16) — guaranteed by callers (byte off = g*16).
#if defined(__has_builtin) && __has_builtin(__builtin_amdgcn_global_load_lds)
__device__ inline void gload_lds16(const void* g, void* l) {
  __builtin_amdgcn_global_load_lds(
      (__attribute__((address_space(1))) void*)g,
      (__attribute__((address_space(3))) void*)l, 16, 0, 0);
}
#else
__device__ inline void gload_lds16(const void* g, void* l) {  // fallback: VGPR path
  *(short8*)l = *(const short8*)g;
}
#endif

// ---------------------------------------------------------------------------
// fp32 -> bf16 cast (weights, once per launch)
// ---------------------------------------------------------------------------
__global__ __launch_bounds__(256) void cast_bf16(const float* __restrict__ src,
                                                 unsigned short* __restrict__ dst,
                                                 int n) {
  int i = (blockIdx.x * 256 + threadIdx.x) * 4;
  if (i < n) {
    float4 v = *(const float4*)&src[i];
    short4v s;
    s.x = (short)f2bf(v.x); s.y = (short)f2bf(v.y);
    s.z = (short)f2bf(v.z); s.w = (short)f2bf(v.w);
    *(short4v*)&dst[i] = s;
  }
}

// ---------------------------------------------------------------------------
// MFMA bf16 GEMM:  C[M,N] = act(A[M,K] @ W[N,K]^T + bias[N]), fp32 accumulate.
// 128x128 tile, BK=32, 256 threads = 4 waves (2x2), 4x4 16x16x32 frags/wave.
// Round-13: 2-phase LDS double-buffer (T3-minimum). Round-12 showed the
// 2-barrier K-loop is latency-bound (FETCH dropped 3.3x, dur -4%; MfmaUtil 22%,
// HBM 15%): the vmcnt(0) drain at each barrier serializes ~600-900cy of HBM
// latency. Now: stage tile t+1 BEFORE computing tile t; ONE barrier per step
// resolves both hazards (RAW on buf[cur] via vmcnt drain; WAR on buf[cur^1],
// all prior reads drained by the same barrier). Accumulation order unchanged.
// W (always) and A (when ABF) staged via global_load_lds width-16 DMA.
// XCD chunked swizzle (T1, round-12: FETCH 270->82 MB on FFN2) retained.
// OBF: 0 = f32 out, 1 = bf16 out, 2 = f32 out + bf16 copy to Cv2.
// ---------------------------------------------------------------------------
template <int RELU, int OBF, int ABF>
__global__ __launch_bounds__(256) void gemm_mfma(const void* __restrict__ Av,
                                                 const unsigned short* __restrict__ W,
                                                 const float* __restrict__ bias,
                                                 void* __restrict__ Cv,
                                                 unsigned short* __restrict__ Cv2,
                                                 int M, int N, int K) {
  __shared__ __align__(16) short As[2][128][32];  // [buf][m][k] bf16
  __shared__ __align__(16) short Ws[2][128][32];  // [buf][n][k] bf16
  const int t = threadIdx.x;
  // XCD swizzle: remap so each XCD gets a contiguous n-fastest tile range.
  const int nwg = (int)(gridDim.x * gridDim.y);
  const int bid = (int)(blockIdx.x + blockIdx.y * gridDim.x);
  const int cpx = nwg >> 3;
  const int swz = (bid & 7) * cpx + (bid >> 3);
  const int m0 = (swz / (int)gridDim.x) * 128;
  const int n0 = (swz % (int)gridDim.x) * 128;
  const int wid = t >> 6, lane = t & 63;
  const int wr = wid >> 1, wc = wid & 1;
  const int l15 = lane & 15, k8 = lane >> 4;

  f32x4 acc[4][4];
#pragma unroll
  for (int i = 0; i < 4; ++i)
#pragma unroll
    for (int j = 0; j < 4; ++j) acc[i][j] = (f32x4)0.0f;

  // Stage one 128x32 K-tile pair into buffer `buf` (async for W and bf16-A).
  auto stage = [&](int kt, int buf) {
#pragma unroll
    for (int i = 0; i < 2; ++i) {
      int g = t + i * 256;
      int r = g >> 2, f = g & 3;
      gload_lds16(W + (size_t)(n0 + r) * K + kt + f * 8,
                  (short*)Ws[buf] + g * 8);
    }
    if (ABF) {
      const unsigned short* A = (const unsigned short*)Av;
#pragma unroll
      for (int i = 0; i < 2; ++i) {
        int g = t + i * 256;
        int r = g >> 2, f = g & 3;
        gload_lds16(A + (size_t)(m0 + r) * K + kt + f * 8,
                    (short*)As[buf] + g * 8);
      }
    } else {
      const float* A = (const float*)Av;
#pragma unroll
      for (int i = 0; i < 4; ++i) {
        int g = t + i * 256;
        int r = g >> 3, f = g & 7;
        float4 v = *(const float4*)(A + (size_t)(m0 + r) * K + kt + f * 4);
        short4v s;
        s.x = (short)f2bf(v.x); s.y = (short)f2bf(v.y);
        s.z = (short)f2bf(v.z); s.w = (short)f2bf(v.w);
        *(short4v*)&As[buf][r][f * 4] = s;
      }
    }
  };

  const int nsteps = K >> 5;
  stage(0, 0);
  int cur = 0;
  for (int s = 0; s < nsteps; ++s) {
    __syncthreads();  // drains vmcnt/lgkmcnt: buf[cur] ready; buf[cur^1] reads done
    if (s + 1 < nsteps) stage((s + 1) * 32, cur ^ 1);  // in flight during compute

    short8 af[4], bg[4];
#pragma unroll
    for (int i = 0; i < 4; ++i)
      af[i] = *(const short8*)&As[cur][wr * 64 + i * 16 + l15][k8 * 8];
#pragma unroll
    for (int j = 0; j < 4; ++j)
      bg[j] = *(const short8*)&Ws[cur][wc * 64 + j * 16 + l15][k8 * 8];
#pragma unroll
    for (int i = 0; i < 4; ++i)
#pragma unroll
      for (int j = 0; j < 4; ++j)
        acc[i][j] = __builtin_amdgcn_mfma_f32_16x16x32_bf16(af[i], bg[j],
                                                            acc[i][j], 0, 0, 0);
    cur ^= 1;
  }

#pragma unroll
  for (int j = 0; j < 4; ++j) {
    int col = n0 + wc * 64 + j * 16 + l15;
    float bv = bias[col];
#pragma unroll
    for (int i = 0; i < 4; ++i) {
      int rbase = m0 + wr * 64 + i * 16 + k8 * 4;
#pragma unroll
      for (int r = 0; r < 4; ++r) {
        float v = acc[i][j][r] + bv;
        if (RELU) v = fmaxf(v, 0.f);
        size_t idx = (size_t)(rbase + r) * N + col;
        if (OBF == 1) {
          ((unsigned short*)Cv)[idx] = f2bf(v);
        } else {
          ((float*)Cv)[idx] = v;
          if (OBF == 2) Cv2[idx] = f2bf(v);
        }
      }
    }
  }
}

// ---------------------------------------------------------------------------
// V transpose: QKV[row][1024 + h*128 + d] -> Vt[(h*128+d)][row]
// Grid (S/64, H, B), 256 threads. Chunk-XOR-swizzled LDS tile.
// ---------------------------------------------------------------------------
__global__ __launch_bounds__(256) void transpose_v(const unsigned short* __restrict__ qkv,
                                                   unsigned short* __restrict__ vt) {
  __shared__ __align__(16) unsigned short T[64][136];
  const int b = blockIdx.z, h = blockIdx.y, s0 = blockIdx.x * 64;
  const int t = threadIdx.x;
#pragma unroll
  for (int it = 0; it < 4; ++it) {
    int c = t + it * 256;
    int s = c >> 4, c8 = c & 15;
    short8 v = *(const short8*)(qkv + (size_t)(b * SEQ + s0 + s) * 1536 + 1024 +
                                h * HDIM + c8 * 8);
    int cs = c8 ^ (s >> 3);
    *(short8*)&T[s][cs * 8] = v;
  }
  __syncthreads();
#pragma unroll
  for (int it = 0; it < 4; ++it) {
    int c = t + it * 256;
    int d = c >> 3, s8 = c & 7;  // output row d (0..127), s-chunk (0..7)
    int j = d >> 3, o = d & 7;
    short8 v;
#pragma unroll
    for (int e = 0; e < 8; ++e) v[e] = (short)T[s8 * 8 + e][(j ^ s8) * 8 + o];
    *(short8*)(vt + (size_t)(h * HDIM + d) * ROWS + b * SEQ + s0 + s8 * 8) = v;
  }
}

// ---------------------------------------------------------------------------
// MFMA flash attention (swapped-operand structure). Validated round 5.
// Grid (S/128, H, B), 512 threads = 8 waves; wave handles 16 q rows.
// ---------------------------------------------------------------------------
__global__ __launch_bounds__(512) void flash_attn_mfma(
    const unsigned short* __restrict__ qkv, const unsigned short* __restrict__ vt,
    unsigned short* __restrict__ o) {
  __shared__ __align__(16) unsigned short Ks[64][136];   // [kv][d]
  __shared__ __align__(16) unsigned short Vs[128][72];   // [d][kv]
  __shared__ __align__(16) unsigned short Ps[8][16][72]; // per-wave [q][kv]
  const int b = blockIdx.z, h = blockIdx.y, q0 = blockIdx.x * 128;
  const int t = threadIdx.x, wid = t >> 6, lane = t & 63;
  const int l15 = lane & 15, hi = lane >> 4;
  const int qrow = q0 + wid * 16 + l15;  // this lane's q (= MFMA col)

  short8 qf[4];
  {
    const unsigned short* qb =
        qkv + (size_t)(b * SEQ + qrow) * 1536 + h * HDIM + 8 * hi;
#pragma unroll
    for (int ks = 0; ks < 4; ++ks) qf[ks] = *(const short8*)(qb + 32 * ks);
  }

  f32x4 oacc[8];
#pragma unroll
  for (int jf = 0; jf < 8; ++jf) oacc[jf] = (f32x4)0.0f;
  float m_i = -1e30f, l_i = 0.f;
  const float scale = 0.08838834764831845f;  // 1/sqrt(128)

  for (int kt = 0; kt < 8; ++kt) {
#pragma unroll
    for (int it = 0; it < 2; ++it) {
      int c = t + it * 512;
      int r = c >> 4, c8 = c & 15;
      short8 v = *(const short8*)(qkv + (size_t)(b * SEQ + kt * 64 + r) * 1536 +
                                  512 + h * HDIM + c8 * 8);
      *(short8*)&Ks[r][c8 * 8] = v;
    }
#pragma unroll
    for (int it = 0; it < 2; ++it) {
      int c = t + it * 512;
      int d = c >> 3, c8 = c & 7;
      short8 v = *(const short8*)(vt + (size_t)(h * HDIM + d) * ROWS + b * SEQ +
                                  kt * 64 + c8 * 8);
      *(short8*)&Vs[d][c8 * 8] = v;
    }
    __syncthreads();

    // S^T[kv][q] = K @ Q^T
    f32x4 st[4];
#pragma unroll
    for (int i = 0; i < 4; ++i) st[i] = (f32x4)0.0f;
#pragma unroll
    for (int ks = 0; ks < 4; ++ks)
#pragma unroll
      for (int i = 0; i < 4; ++i) {
        short8 kf = *(const short8*)&Ks[i * 16 + l15][32 * ks + 8 * hi];
        st[i] = __builtin_amdgcn_mfma_f32_16x16x32_bf16(kf, qf[ks], st[i], 0, 0, 0);
      }

    // online softmax (lane owns q-col; kv = 16i+4hi+r)
    float p[16];
    float pmax = -1e30f;
#pragma unroll
    for (int i = 0; i < 4; ++i)
#pragma unroll
      for (int r = 0; r < 4; ++r) {
        float sv = st[i][r] * scale;
        p[i * 4 + r] = sv;
        pmax = fmaxf(pmax, sv);
      }
    pmax = fmaxf(pmax, __shfl_xor(pmax, 16));
    pmax = fmaxf(pmax, __shfl_xor(pmax, 32));
    float mn = fmaxf(m_i, pmax);
    float al = __expf(m_i - mn);
    float rsum = 0.f;
#pragma unroll
    for (int e = 0; e < 16; ++e) {
      p[e] = __expf(p[e] - mn);
      rsum += p[e];
    }
    rsum += __shfl_xor(rsum, 16);
    rsum += __shfl_xor(rsum, 32);
    l_i = l_i * al + rsum;
    m_i = mn;
#pragma unroll
    for (int jf = 0; jf < 8; ++jf) oacc[jf] *= al;

    // P -> bf16 in per-wave LDS
#pragma unroll
    for (int i = 0; i < 4; ++i) {
      uint2 u;
      u.x = (unsigned int)f2bf(p[i * 4 + 0]) | ((unsigned int)f2bf(p[i * 4 + 1]) << 16);
      u.y = (unsigned int)f2bf(p[i * 4 + 2]) | ((unsigned int)f2bf(p[i * 4 + 3]) << 16);
      *(uint2*)&Ps[wid][l15][16 * i + 4 * hi] = u;
    }

    // O^T[d][q] += Vt @ P^T
#pragma unroll
    for (int ks2 = 0; ks2 < 2; ++ks2) {
      short8 pf = *(const short8*)&Ps[wid][l15][32 * ks2 + 8 * hi];
#pragma unroll
      for (int jf = 0; jf < 8; ++jf) {
        short8 vf = *(const short8*)&Vs[jf * 16 + l15][32 * ks2 + 8 * hi];
        oacc[jf] = __builtin_amdgcn_mfma_f32_16x16x32_bf16(vf, pf, oacc[jf], 0, 0, 0);
      }
    }
    __syncthreads();
  }

  const float inv = 1.0f / l_i;
  unsigned short* ob = o + (size_t)(b * SEQ + qrow) * DMODEL + h * HDIM;
#pragma unroll
  for (int jf = 0; jf < 8; ++jf) {
    uint2 u;
    u.x = (unsigned int)f2bf(oacc[jf][0] * inv) |
          ((unsigned int)f2bf(oacc[jf][1] * inv) << 16);
    u.y = (unsigned int)f2bf(oacc[jf][2] * inv) |
          ((unsigned int)f2bf(oacc[jf][3] * inv) << 16);
    *(uint2*)(ob + 16 * jf + 4 * hi) = u;
  }
}

// ---------------------------------------------------------------------------
// y[row] = LN(x[row] + r[row]) * g + b  (row 512, 1 block/row)
// Optionally also writes bf16 copy yb (feeds next GEMM's DMA-staged A).
// ---------------------------------------------------------------------------
__global__ __launch_bounds__(256) void add_ln(const float* __restrict__ x,
                                              const float* __restrict__ r,
                                              const float* __restrict__ g,
                                              const float* __restrict__ beta,
                                              float* __restrict__ y,
                                              unsigned short* __restrict__ yb) {
  const int row = blockIdx.x, t = threadIdx.x;
  const float* xr = x + (size_t)row * DMODEL;
  const float* rr = r + (size_t)row * DMODEL;
  float a0 = xr[t] + rr[t];
  float a1 = xr[t + 256] + rr[t + 256];
  float sum = a0 + a1, sq = a0 * a0 + a1 * a1;
#pragma unroll
  for (int m = 1; m < 64; m <<= 1) {
    sum += __shfl_xor(sum, m);
    sq += __shfl_xor(sq, m);
  }
  __shared__ float ssum[4], ssq[4];
  const int w = t >> 6;
  if ((t & 63) == 0) { ssum[w] = sum; ssq[w] = sq; }
  __syncthreads();
  sum = ssum[0] + ssum[1] + ssum[2] + ssum[3];
  sq = ssq[0] + ssq[1] + ssq[2] + ssq[3];
  const float mean = sum * (1.0f / DMODEL);
  const float var = sq * (1.0f / DMODEL) - mean * mean;
  const float rinv = rsqrtf(var + 1e-5f);
  float v0 = (a0 - mean) * rinv * g[t] + beta[t];
  float v1 = (a1 - mean) * rinv * g[t + 256] + beta[t + 256];
  float* yr = y + (size_t)row * DMODEL;
  yr[t] = v0;
  yr[t + 256] = v1;
  if (yb) {
    yb[(size_t)row * DMODEL + t] = f2bf(v0);
    yb[(size_t)row * DMODEL + t + 256] = f2bf(v1);
  }
}

// ---------------------------------------------------------------------------
// Pooling, parallelized (round-5 fix: pool_cls was latency-bound at 190 µs,
// 64 blocks / 1.3% occupancy / 1% HBM). Three stages.
// ---------------------------------------------------------------------------
__global__ __launch_bounds__(256) void zero_pool(float* __restrict__ pooled) {
  pooled[blockIdx.x * 256 + threadIdx.x] = 0.f;
}

__global__ __launch_bounds__(256) void pool_partial(const float* __restrict__ x,
                                                    const int* __restrict__ mask,
                                                    float* __restrict__ pooled) {
  const int b = blockIdx.x >> 4;          // batch
  const int s0 = (blockIdx.x & 15) * 32;  // chunk of 32 seq rows
  const int t = threadIdx.x;
  if (mask[b * SEQ + s0] == 0) return;  // prefix mask: whole chunk inactive (uniform)
  float a0 = 0.f, a1 = 0.f;
  for (int s = 0; s < 32; ++s) {
    int row = b * SEQ + s0 + s;
    if (mask[row]) {  // uniform across block
      const float* xr = x + (size_t)row * DMODEL;
      a0 += xr[t];
      a1 += xr[t + 256];
    }
  }
  atomicAdd(&pooled[b * DMODEL + t], a0);
  atomicAdd(&pooled[b * DMODEL + t + 256], a1);
}

__global__ __launch_bounds__(256) void cls_head(const float* __restrict__ pooled,
                                                const int* __restrict__ mask,
                                                const float* __restrict__ wc,
                                                const float* __restrict__ bc,
                                                float* __restrict__ out) {
  const int b = blockIdx.x, t = threadIdx.x;
  float c = (float)(mask[b * SEQ + t] + mask[b * SEQ + t + 256]);
#pragma unroll
  for (int m = 1; m < 64; m <<= 1) c += __shfl_xor(c, m);
  __shared__ float cs[4], r0s[4], r1s[4];
  const int w = t >> 6;
  if ((t & 63) == 0) cs[w] = c;
  __syncthreads();
  const float cnt = cs[0] + cs[1] + cs[2] + cs[3];
  const float inv = 1.0f / cnt;
  const float p0 = pooled[b * DMODEL + t] * inv;
  const float p1 = pooled[b * DMODEL + t + 256] * inv;
  float l0 = p0 * wc[t] + p1 * wc[t + 256];
  float l1 = p0 * wc[DMODEL + t] + p1 * wc[DMODEL + t + 256];
#pragma unroll
  for (int m = 1; m < 64; m <<= 1) {
    l0 += __shfl_xor(l0, m);
    l1 += __shfl_xor(l1, m);
  }
  if ((t & 63) == 0) { r0s[w] = l0; r1s[w] = l1; }
  __syncthreads();
  if (t == 0) {
    out[b * 2 + 0] = r0s[0] + r0s[1] + r0s[2] + r0s[3] + bc[0];
    out[b * 2 + 1] = r1s[0] + r1s[1] + r1s[2] + r1s[3] + bc[1];
  }
}

// ---------------------------------------------------------------------------
extern "C" void kernel_launch(void* const* d_in, const int* in_sizes, int n_in,
                              void* d_out, int out_size, void* d_ws, size_t ws_size,
                              hipStream_t stream) {
  (void)in_sizes; (void)n_in; (void)out_size; (void)ws_size;
  const float* vf    = (const float*)d_in[0];
  const int*   mask  = (const int*)d_in[1];
  const float* w_img = (const float*)d_in[2];
  const float* b_img = (const float*)d_in[3];
  const float* in_w  = (const float*)d_in[4];
  const float* in_b  = (const float*)d_in[5];
  const float* out_w = (const float*)d_in[6];
  const float* out_b = (const float*)d_in[7];
  const float* ln1_g = (const float*)d_in[8];
  const float* ln1_b = (const float*)d_in[9];
  const float* w1    = (const float*)d_in[10];
  const float* b1    = (const float*)d_in[11];
  const float* w2    = (const float*)d_in[12];
  const float* b2    = (const float*)d_in[13];
  const float* ln2_g = (const float*)d_in[14];
  const float* ln2_b = (const float*)d_in[15];
  const float* w_cls = (const float*)d_in[16];
  const float* b_cls = (const float*)d_in[17];
  float* out = (float*)d_out;

  // Workspace layout (peak 359.125 MB < 360 proven; live ranges audited r9):
  //   X    f32 [0,64)      dead after ln1          Xb  bf16 [64,96)  dead after QKV
  //   QKV  bf16 [96,192)   dead after flash        Vt  bf16 [192,224) dead after flash
  //   Obf  bf16 [224,256)  dead after out-proj     P   f32 [256,320) dead after ln1
  //   X1   f32 [64,128)    dead after ln2          X1b bf16 [128,160) dead after FFN1
  //   HH   bf16 [160,288)  dead after FFN2         Fo  f32 [0,64)
  //   X2   f32 [288,352)   wb [352,~358.75)        pooled [359,359.125)
  char* ws = (char*)d_ws;
  const size_t MB = 1ull << 20;
  float*          X   = (float*)(ws + 0 * MB);
  unsigned short* Xb  = (unsigned short*)(ws + 64 * MB);
  unsigned short* QKV = (unsigned short*)(ws + 96 * MB);
  unsigned short* Vt  = (unsigned short*)(ws + 192 * MB);
  unsigned short* Obf = (unsigned short*)(ws + 224 * MB);
  float*          P   = (float*)(ws + 256 * MB);
  float*          X1  = (float*)(ws + 64 * MB);
  unsigned short* X1b = (unsigned short*)(ws + 128 * MB);
  unsigned short* HH  = (unsigned short*)(ws + 160 * MB);
  float*          Fo  = (float*)(ws + 0 * MB);
  float*          X2  = (float*)(ws + 288 * MB);
  unsigned short* wb  = (unsigned short*)(ws + 352 * MB);
  unsigned short* wb_img = wb;                   // 512*768
  unsigned short* wb_in  = wb_img + 512 * 768;   // 1536*512
  unsigned short* wb_out = wb_in + 1536 * 512;   // 512*512
  unsigned short* wb_1   = wb_out + 512 * 512;   // 2048*512
  unsigned short* wb_2   = wb_1 + 2048 * 512;    // 512*2048
  float*          pooled = (float*)(ws + 359 * MB);  // [64][512] f32

  dim3 blk(256);
  cast_bf16<<<dim3(512 * 768 / 1024), blk, 0, stream>>>(w_img, wb_img, 512 * 768);
  cast_bf16<<<dim3(1536 * 512 / 1024), blk, 0, stream>>>(in_w, wb_in, 1536 * 512);
  cast_bf16<<<dim3(512 * 512 / 1024), blk, 0, stream>>>(out_w, wb_out, 512 * 512);
  cast_bf16<<<dim3(2048 * 512 / 1024), blk, 0, stream>>>(w1, wb_1, 2048 * 512);
  cast_bf16<<<dim3(512 * 2048 / 1024), blk, 0, stream>>>(w2, wb_2, 512 * 2048);
  zero_pool<<<dim3(BATCH * DMODEL / 256), blk, 0, stream>>>(pooled);

  // X,Xb = relu(vf @ w_img^T + b_img)   (fp32 A path; dual-output)
  gemm_mfma<1, 2, 0><<<dim3(DMODEL / 128, ROWS / 128), blk, 0, stream>>>(
      vf, wb_img, b_img, X, Xb, ROWS, DMODEL, D_INF);
  // QKV(bf16) = Xb @ in_w^T + in_b      (full-DMA staging)
  gemm_mfma<0, 1, 1><<<dim3(3 * DMODEL / 128, ROWS / 128), blk, 0, stream>>>(
      Xb, wb_in, in_b, QKV, nullptr, ROWS, 3 * DMODEL, DMODEL);
  transpose_v<<<dim3(SEQ / 64, NHEAD, BATCH), blk, 0, stream>>>(QKV, Vt);
  flash_attn_mfma<<<dim3(SEQ / 128, NHEAD, BATCH), dim3(512), 0, stream>>>(QKV, Vt, Obf);
  // P = Obf @ out_w^T + out_b           (full-DMA staging)
  gemm_mfma<0, 0, 1><<<dim3(DMODEL / 128, ROWS / 128), blk, 0, stream>>>(
      Obf, wb_out, out_b, P, nullptr, ROWS, DMODEL, DMODEL);
  add_ln<<<dim3(ROWS), blk, 0, stream>>>(X, P, ln1_g, ln1_b, X1, X1b);
  // HH(bf16) = relu(X1b @ w1^T + b1)    (full-DMA staging)
  gemm_mfma<1, 1, 1><<<dim3(FFDIM / 128, ROWS / 128), blk, 0, stream>>>(
      X1b, wb_1, b1, HH, nullptr, ROWS, FFDIM, DMODEL);
  // Fo = HH @ w2^T + b2                 (full-DMA staging)
  gemm_mfma<0, 0, 1><<<dim3(DMODEL / 128, ROWS / 128), blk, 0, stream>>>(
      HH, wb_2, b2, Fo, nullptr, ROWS, DMODEL, FFDIM);
  add_ln<<<dim3(ROWS), blk, 0, stream>>>(X1, Fo, ln2_g, ln2_b, X2, nullptr);
  pool_partial<<<dim3(BATCH * 16), blk, 0, stream>>>(X2, mask, pooled);
  cls_head<<<dim3(BATCH), blk, 0, stream>>>(pooled, mask, w_cls, b_cls, out);
}